// Round 1
// baseline (4592.987 us; speedup 1.0000x reference)
//
#include <hip/hip_runtime.h>
#include <math.h>

#define BATCH 8
#define SEQ   2048
#define TOK   (BATCH*SEQ)     // 16384
#define CIN   32
#define DM    512
#define DFF   2048
#define NH    8
#define HD    64
#define NSAMP 24
#define NTOP  24
#define EPS   1e-5f

// ---------------- Threefry-2x32 (matches JAX rolled loop) ----------------
__device__ __forceinline__ void tf_round(unsigned &x0, unsigned &x1, int r) {
    x0 += x1;
    x1 = (x1 << r) | (x1 >> (32 - r));
    x1 ^= x0;
}
__device__ __forceinline__ void threefry(unsigned k0, unsigned k1,
                                         unsigned c0, unsigned c1,
                                         unsigned &o0, unsigned &o1) {
    unsigned ks0 = k0, ks1 = k1, ks2 = k0 ^ k1 ^ 0x1BD11BDAu;
    unsigned x0 = c0 + ks0, x1 = c1 + ks1;
    tf_round(x0,x1,13); tf_round(x0,x1,15); tf_round(x0,x1,26); tf_round(x0,x1,6);
    x0 += ks1; x1 += ks2 + 1u;
    tf_round(x0,x1,17); tf_round(x0,x1,29); tf_round(x0,x1,16); tf_round(x0,x1,24);
    x0 += ks2; x1 += ks0 + 2u;
    tf_round(x0,x1,13); tf_round(x0,x1,15); tf_round(x0,x1,26); tf_round(x0,x1,6);
    x0 += ks0; x1 += ks1 + 3u;
    tf_round(x0,x1,17); tf_round(x0,x1,29); tf_round(x0,x1,16); tf_round(x0,x1,24);
    x0 += ks1; x1 += ks2 + 4u;
    tf_round(x0,x1,13); tf_round(x0,x1,15); tf_round(x0,x1,26); tf_round(x0,x1,6);
    x0 += ks2; x1 += ks0 + 5u;
    o0 = x0; o1 = x1;
}

// idx_sample for both layers: replicates jax.random.randint(fold_in(key(42),li),(2048,24),0,2048)
__global__ void sample_kernel(int* __restrict__ idx_sample) {
    const int HALF = (SEQ * NSAMP) / 2;  // 24576
    int p = blockIdx.x * blockDim.x + threadIdx.x;
    int li = blockIdx.y;
    if (p >= HALF) return;
    unsigned f0, f1;
    threefry(0u, 42u, 0u, (unsigned)li, f0, f1);          // fold_in
    unsigned a0, a1, b0, b1;
    threefry(f0, f1, 0u, 2u, a0, a1);                     // split
    threefry(f0, f1, 1u, 3u, b0, b1);
    // k2 (lower-bits key) = (a1, b1); multiplier==0 since 2^16 % 2048 == 0
    unsigned o0, o1;
    threefry(a1, b1, (unsigned)p, (unsigned)(p + HALF), o0, o1);
    idx_sample[li * SEQ * NSAMP + p]        = (int)(o0 & (SEQ - 1));
    idx_sample[li * SEQ * NSAMP + p + HALF] = (int)(o1 & (SEQ - 1));
}

// ---------------- input layernorm over C_IN=32 ----------------
__global__ __launch_bounds__(256) void ln_in_kernel(const float* __restrict__ x,
        const float* __restrict__ g, const float* __restrict__ b,
        float* __restrict__ out) {
    int t = blockIdx.x * blockDim.x + threadIdx.x;
    if (t >= TOK) return;
    const float* xr = x + (size_t)t * CIN;
    float vals[CIN];
    float s = 0.f;
#pragma unroll
    for (int c = 0; c < CIN; c++) { vals[c] = xr[c]; s += vals[c]; }
    float m = s * (1.f / CIN);
    float v = 0.f;
#pragma unroll
    for (int c = 0; c < CIN; c++) { float d = vals[c] - m; v += d * d; }
    v *= (1.f / CIN);
    float inv = rsqrtf(v + EPS);
    float* orow = out + (size_t)t * CIN;
#pragma unroll
    for (int c = 0; c < CIN; c++) orow[c] = (vals[c] - m) * inv * g[c] + b[c];
}

// ---------------- token conv + pos emb + time emb ----------------
__global__ __launch_bounds__(256) void embed_kernel(const float* __restrict__ xln,
        const float* __restrict__ tfeat, const float* __restrict__ Wtok,
        const float* __restrict__ Wtime, const float* __restrict__ btime,
        float* __restrict__ h) {
    __shared__ float xs[96];
    __shared__ float tf4[4];
    int t = blockIdx.x;
    int b = t / SEQ, l = t % SEQ;
    int tid = threadIdx.x;
    if (tid < 96) {
        int w = tid / 32, c = tid % 32;
        int lw = (l - 1 + w + SEQ) % SEQ;  // wrap pad
        xs[tid] = xln[((size_t)b * SEQ + lw) * CIN + c];
    }
    if (tid < 4) tf4[tid] = tfeat[((size_t)b * SEQ + l) * 4 + tid];
    __syncthreads();
    const float c1 = -0.017988946039016f;  // -ln(10000)/512
    for (int o = tid; o < DM; o += 256) {
        float acc = btime[o];
        for (int j = 0; j < 96; j++) acc += xs[j] * Wtok[j * DM + o];
        acc += tf4[0] * Wtime[o * 4 + 0] + tf4[1] * Wtime[o * 4 + 1]
             + tf4[2] * Wtime[o * 4 + 2] + tf4[3] * Wtime[o * 4 + 3];
        int i2 = o & ~1;
        float div = expf((float)i2 * c1);
        float arg = (float)l * div;
        float pe = (o & 1) ? cosf(arg) : sinf(arg);
        h[(size_t)t * DM + o] = acc + pe;
    }
}

// ---------------- generic fp32 GEMM: C = A[MxK] * W[NxK]^T + bias (+res)(+relu) ----------------
template<bool RELU, bool RES>
__global__ __launch_bounds__(256) void gemm_tn(const float* __restrict__ A,
        const float* __restrict__ W, const float* __restrict__ bias,
        const float* Rsd, float* C, int M, int N, int K) {
    __shared__ float As[16][64];
    __shared__ float Ws[16][64];
    int tid = threadIdx.x;
    int tx = tid % 16, ty = tid / 16;
    int m0 = blockIdx.y * 64, n0 = blockIdx.x * 64;
    int lr = tid / 4;           // 0..63
    int lc = (tid % 4) * 4;     // 0,4,8,12
    float acc[4][4] = {};
    for (int k0 = 0; k0 < K; k0 += 16) {
        float4 av = *(const float4*)&A[(size_t)(m0 + lr) * K + k0 + lc];
        float4 wv = *(const float4*)&W[(size_t)(n0 + lr) * K + k0 + lc];
        __syncthreads();
        As[lc + 0][lr] = av.x; As[lc + 1][lr] = av.y;
        As[lc + 2][lr] = av.z; As[lc + 3][lr] = av.w;
        Ws[lc + 0][lr] = wv.x; Ws[lc + 1][lr] = wv.y;
        Ws[lc + 2][lr] = wv.z; Ws[lc + 3][lr] = wv.w;
        __syncthreads();
#pragma unroll
        for (int kk = 0; kk < 16; kk++) {
            float4 a4 = *(const float4*)&As[kk][ty * 4];
            float4 b4 = *(const float4*)&Ws[kk][tx * 4];
            acc[0][0] += a4.x * b4.x; acc[0][1] += a4.x * b4.y;
            acc[0][2] += a4.x * b4.z; acc[0][3] += a4.x * b4.w;
            acc[1][0] += a4.y * b4.x; acc[1][1] += a4.y * b4.y;
            acc[1][2] += a4.y * b4.z; acc[1][3] += a4.y * b4.w;
            acc[2][0] += a4.z * b4.x; acc[2][1] += a4.z * b4.y;
            acc[2][2] += a4.z * b4.z; acc[2][3] += a4.z * b4.w;
            acc[3][0] += a4.w * b4.x; acc[3][1] += a4.w * b4.y;
            acc[3][2] += a4.w * b4.z; acc[3][3] += a4.w * b4.w;
        }
    }
#pragma unroll
    for (int i = 0; i < 4; i++) {
        int m = m0 + ty * 4 + i;
#pragma unroll
        for (int j = 0; j < 4; j++) {
            int n = n0 + tx * 4 + j;
            float v = acc[i][j] + bias[n];
            if (RES) v += Rsd[(size_t)m * N + n];
            if (RELU) v = fmaxf(v, 0.f);
            C[(size_t)m * N + n] = v;
        }
    }
}

// ---------------- M = max(QK_sample) - sum(QK_sample)/L : one wave per (b,h,l) ----------------
__global__ __launch_bounds__(256) void qk_sample_kernel(const float* __restrict__ q,
        const float* __restrict__ k, const int* __restrict__ idx_sample,
        float* __restrict__ Mout) {
    int r = (blockIdx.x * 256 + threadIdx.x) / 64;
    int lane = threadIdx.x & 63;
    if (r >= BATCH * NH * SEQ) return;
    int b = r / (NH * SEQ);
    int head = (r / SEQ) % NH;
    int l = r % SEQ;
    float qd = q[((size_t)(b * SEQ + l)) * DM + head * HD + lane];
    float mx = -INFINITY, sm = 0.f;
    for (int s = 0; s < NSAMP; s++) {
        int idx = idx_sample[l * NSAMP + s];
        float kd = k[((size_t)(b * SEQ + idx)) * DM + head * HD + lane];
        float p = qd * kd;
#pragma unroll
        for (int off = 32; off > 0; off >>= 1) p += __shfl_xor(p, off);
        mx = fmaxf(mx, p);
        sm += p;
    }
    if (lane == 0) Mout[r] = mx - sm * (1.f / SEQ);
}

// ---------------- top-24 (stable, ties -> lower index) per (b,h) ----------------
__global__ __launch_bounds__(256) void topk_kernel(const float* __restrict__ Mbuf,
        int* __restrict__ idx_top) {
    __shared__ float vals[SEQ];
    __shared__ float rv[256];
    __shared__ int   ri[256];
    int bh = blockIdx.x;
    int tid = threadIdx.x;
    const float* Mr = Mbuf + (size_t)bh * SEQ;
    for (int i = tid; i < SEQ; i += 256) vals[i] = Mr[i];
    __syncthreads();
    for (int it = 0; it < NTOP; it++) {
        float best = -INFINITY; int bi = SEQ;
        for (int i = tid; i < SEQ; i += 256) {
            float v = vals[i];
            if (v > best || (v == best && i < bi)) { best = v; bi = i; }
        }
        rv[tid] = best; ri[tid] = bi;
        __syncthreads();
        for (int s = 128; s > 0; s >>= 1) {
            if (tid < s) {
                float v2 = rv[tid + s]; int i2 = ri[tid + s];
                if (v2 > rv[tid] || (v2 == rv[tid] && i2 < ri[tid])) { rv[tid] = v2; ri[tid] = i2; }
            }
            __syncthreads();
        }
        if (tid == 0) { idx_top[bh * NTOP + it] = ri[0]; vals[ri[0]] = -INFINITY; }
        __syncthreads();
    }
}

// ---------------- V mean over keys per (b,h) ----------------
__global__ void vmean_kernel(const float* __restrict__ v, float* __restrict__ vmean) {
    int bh = blockIdx.x;
    int d = threadIdx.x;  // 64
    int b = bh / NH, head = bh % NH;
    float s = 0.f;
    for (int l = 0; l < SEQ; l++)
        s += v[((size_t)(b * SEQ + l)) * DM + head * HD + d];
    vmean[bh * HD + d] = s * (1.f / SEQ);
}

// ---------------- fill context with V-mean ----------------
__global__ void fillctx_kernel(const float* __restrict__ vmean, float* __restrict__ out) {
    int e = blockIdx.x * 256 + threadIdx.x;  // < TOK*DM = 8388608
    int c = e % DM;
    int b = e / (SEQ * DM);
    out[e] = vmean[(b * NH + (c / HD)) * HD + (c % HD)];
}

// ---------------- full attention for the 24 selected queries ----------------
__global__ __launch_bounds__(256) void spattn_kernel(const float* __restrict__ q,
        const float* __restrict__ k, const float* __restrict__ v,
        const int* __restrict__ idx_top, float* __restrict__ out) {
    __shared__ float qrow[HD];
    __shared__ float sc[SEQ];
    __shared__ float red[256];
    int blk = blockIdx.x;                 // b*NH*NTOP
    int u = blk % NTOP;
    int bh = blk / NTOP;
    int head = bh % NH, b = bh / NH;
    int tid = threadIdx.x;
    int qi = idx_top[bh * NTOP + u];
    if (tid < HD) qrow[tid] = q[((size_t)(b * SEQ + qi)) * DM + head * HD + tid];
    __syncthreads();
    for (int kk = tid; kk < SEQ; kk += 256) {
        const float* kr = k + ((size_t)(b * SEQ + kk)) * DM + head * HD;
        float dot = 0.f;
#pragma unroll
        for (int d = 0; d < HD; d += 4) {
            float4 k4 = *(const float4*)&kr[d];
            dot += qrow[d] * k4.x + qrow[d + 1] * k4.y + qrow[d + 2] * k4.z + qrow[d + 3] * k4.w;
        }
        sc[kk] = dot * 0.125f;  // 1/sqrt(64)
    }
    __syncthreads();
    float lm = -INFINITY;
    for (int kk = tid; kk < SEQ; kk += 256) lm = fmaxf(lm, sc[kk]);
    red[tid] = lm; __syncthreads();
    for (int s = 128; s > 0; s >>= 1) { if (tid < s) red[tid] = fmaxf(red[tid], red[tid + s]); __syncthreads(); }
    float mx = red[0];
    __syncthreads();
    float ls = 0.f;
    for (int kk = tid; kk < SEQ; kk += 256) { float e = expf(sc[kk] - mx); sc[kk] = e; ls += e; }
    red[tid] = ls; __syncthreads();
    for (int s = 128; s > 0; s >>= 1) { if (tid < s) red[tid] += red[tid + s]; __syncthreads(); }
    float ssum = red[0];
    __syncthreads();
    int d = tid % HD, seg = tid / HD;     // 4 segments of 512 keys
    float pa = 0.f;
    for (int kk = seg * 512; kk < (seg + 1) * 512; kk++)
        pa += sc[kk] * v[((size_t)(b * SEQ + kk)) * DM + head * HD + d];
    red[tid] = pa; __syncthreads();
    if (tid < HD) {
        float upd = (red[tid] + red[tid + 64] + red[tid + 128] + red[tid + 192]) / ssum;
        out[((size_t)(b * SEQ + qi)) * DM + head * HD + tid] = upd;
    }
}

// ---------------- layernorm over DM=512 ----------------
__global__ __launch_bounds__(256) void ln_kernel(const float* src,
        const float* __restrict__ g, const float* __restrict__ b, float* dst) {
    __shared__ float red[256];
    int t = blockIdx.x, tid = threadIdx.x;
    const float* xr = src + (size_t)t * DM;
    float x0 = xr[tid], x1 = xr[tid + 256];
    red[tid] = x0 + x1; __syncthreads();
    for (int s = 128; s > 0; s >>= 1) { if (tid < s) red[tid] += red[tid + s]; __syncthreads(); }
    float m = red[0] * (1.f / DM);
    __syncthreads();
    float d0 = x0 - m, d1 = x1 - m;
    red[tid] = d0 * d0 + d1 * d1; __syncthreads();
    for (int s = 128; s > 0; s >>= 1) { if (tid < s) red[tid] += red[tid + s]; __syncthreads(); }
    float inv = rsqrtf(red[0] * (1.f / DM) + EPS);
    float* dr = dst + (size_t)t * DM;
    dr[tid] = d0 * inv * g[tid] + b[tid];
    dr[tid + 256] = d1 * inv * g[tid + 256] + b[tid + 256];
}

// ---------------- prediction head on last token ----------------
__global__ __launch_bounds__(256) void head_kernel(const float* __restrict__ hfin,
        const float* __restrict__ Wpre, const float* __restrict__ bpre,
        const float* __restrict__ Wfc, const float* __restrict__ bfc,
        float* __restrict__ out) {
    __shared__ float last[DM];
    __shared__ float red[256];
    int b = blockIdx.x, tid = threadIdx.x;
    const float* hr = hfin + ((size_t)(b * SEQ + SEQ - 1)) * DM;
    last[tid] = hr[tid];
    last[tid + 256] = hr[tid + 256];
    __syncthreads();
    float acc = bpre[tid];
    for (int c = 0; c < DM; c++) acc += last[c] * Wpre[tid * DM + c];
    acc = fmaxf(acc, 0.f);
    red[tid] = acc * Wfc[tid];
    __syncthreads();
    for (int s = 128; s > 0; s >>= 1) { if (tid < s) red[tid] += red[tid + s]; __syncthreads(); }
    if (tid == 0) out[b] = red[0] + bfc[0];
}

extern "C" void kernel_launch(void* const* d_in, const int* in_sizes, int n_in,
                              void* d_out, int out_size, void* d_ws, size_t ws_size,
                              hipStream_t stream) {
    (void)in_sizes; (void)n_in; (void)out_size; (void)ws_size;
    const float* x      = (const float*)d_in[0];
    const float* tfeat  = (const float*)d_in[1];
    const float* g_in   = (const float*)d_in[2];
    const float* b_in   = (const float*)d_in[3];
    const float* W_tok  = (const float*)d_in[4];
    const float* W_time = (const float*)d_in[5];
    const float* b_time = (const float*)d_in[6];
    const float* Wq     = (const float*)d_in[7];
    const float* bq     = (const float*)d_in[8];
    const float* Wk     = (const float*)d_in[9];
    const float* bk     = (const float*)d_in[10];
    const float* Wv     = (const float*)d_in[11];
    const float* bv     = (const float*)d_in[12];
    const float* Wo     = (const float*)d_in[13];
    const float* bo     = (const float*)d_in[14];
    const float* W1     = (const float*)d_in[15];
    const float* b1     = (const float*)d_in[16];
    const float* W2     = (const float*)d_in[17];
    const float* b2     = (const float*)d_in[18];
    const float* g1     = (const float*)d_in[19];
    const float* be1    = (const float*)d_in[20];
    const float* g2     = (const float*)d_in[21];
    const float* be2    = (const float*)d_in[22];
    const float* g_enc  = (const float*)d_in[23];
    const float* b_enc  = (const float*)d_in[24];
    const float* W_pre  = (const float*)d_in[25];
    const float* b_pre  = (const float*)d_in[26];
    const float* W_fc   = (const float*)d_in[27];
    const float* b_fc   = (const float*)d_in[28];
    float* out = (float*)d_out;

    char* ws = (char*)d_ws;
    float* h    = (float*)(ws);                      // 33.5 MB
    float* tmp  = (float*)(ws + 33554432);           // 33.5 MB
    float* Cbig = (float*)(ws + 67108864);           // 134.2 MB (q,k,v OR ffn act)
    float* qb = Cbig;
    float* kb = Cbig + 8388608;
    float* vb = Cbig + 16777216;
    float* xln        = (float*)(ws + 201326592);    // 2 MB
    float* Mbuf       = (float*)(ws + 203423744);    // 0.5 MB
    float* vmean      = (float*)(ws + 203948032);
    int*   idx_sample = (int*)(ws + 203964416);
    int*   idx_top    = (int*)(ws + 204357632);

    ln_in_kernel<<<TOK / 256, 256, 0, stream>>>(x, g_in, b_in, xln);
    embed_kernel<<<TOK, 256, 0, stream>>>(xln, tfeat, W_tok, W_time, b_time, h);
    sample_kernel<<<dim3(96, 2), 256, 0, stream>>>(idx_sample);

    for (int li = 0; li < 2; li++) {
        const float* Wq_i = Wq + (size_t)li * DM * DM;
        const float* Wk_i = Wk + (size_t)li * DM * DM;
        const float* Wv_i = Wv + (size_t)li * DM * DM;
        const float* Wo_i = Wo + (size_t)li * DM * DM;
        const float* W1_i = W1 + (size_t)li * DFF * DM;
        const float* W2_i = W2 + (size_t)li * DM * DFF;
        const float* bq_i = bq + (size_t)li * DM;
        const float* bk_i = bk + (size_t)li * DM;
        const float* bv_i = bv + (size_t)li * DM;
        const float* bo_i = bo + (size_t)li * DM;
        const float* b1_i = b1 + (size_t)li * DFF;
        const float* b2_i = b2 + (size_t)li * DM;
        const float* g1_i = g1 + (size_t)li * DM;
        const float* be1_i = be1 + (size_t)li * DM;
        const float* g2_i = g2 + (size_t)li * DM;
        const float* be2_i = be2 + (size_t)li * DM;

        dim3 gQ(DM / 64, TOK / 64);
        gemm_tn<false, false><<<gQ, 256, 0, stream>>>(h, Wq_i, bq_i, nullptr, qb, TOK, DM, DM);
        gemm_tn<false, false><<<gQ, 256, 0, stream>>>(h, Wk_i, bk_i, nullptr, kb, TOK, DM, DM);
        gemm_tn<false, false><<<gQ, 256, 0, stream>>>(h, Wv_i, bv_i, nullptr, vb, TOK, DM, DM);

        qk_sample_kernel<<<(BATCH * NH * SEQ) / 4, 256, 0, stream>>>(
            qb, kb, idx_sample + li * SEQ * NSAMP, Mbuf);
        topk_kernel<<<BATCH * NH, 256, 0, stream>>>(Mbuf, idx_top);
        vmean_kernel<<<BATCH * NH, 64, 0, stream>>>(vb, vmean);
        fillctx_kernel<<<(TOK * DM) / 256, 256, 0, stream>>>(vmean, tmp);
        spattn_kernel<<<BATCH * NH * NTOP, 256, 0, stream>>>(qb, kb, vb, idx_top, tmp);

        gemm_tn<false, true><<<gQ, 256, 0, stream>>>(tmp, Wo_i, bo_i, h, h, TOK, DM, DM);
        ln_kernel<<<TOK, 256, 0, stream>>>(h, g1_i, be1_i, h);

        gemm_tn<true, false><<<dim3(DFF / 64, TOK / 64), 256, 0, stream>>>(
            h, W1_i, b1_i, nullptr, Cbig, TOK, DFF, DM);
        gemm_tn<false, true><<<dim3(DM / 64, TOK / 64), 256, 0, stream>>>(
            Cbig, W2_i, b2_i, h, tmp, TOK, DM, DFF);
        ln_kernel<<<TOK, 256, 0, stream>>>(tmp, g2_i, be2_i, h);
    }

    ln_kernel<<<TOK, 256, 0, stream>>>(h, g_enc, b_enc, tmp);
    head_kernel<<<BATCH, 256, 0, stream>>>(tmp, W_pre, b_pre, W_fc, b_fc, out);
}

// Round 2
// 2589.125 us; speedup vs baseline: 1.7740x; 1.7740x over previous
//
#include <hip/hip_runtime.h>
#include <math.h>

#define BATCH 8
#define SEQ   2048
#define TOK   (BATCH*SEQ)     // 16384
#define CIN   32
#define DM    512
#define DFF   2048
#define NH    8
#define HD    64
#define NSAMP 24
#define NTOP  24
#define EPS   1e-5f

typedef unsigned int u32;
typedef __attribute__((ext_vector_type(8))) short short8;
typedef __attribute__((ext_vector_type(4))) float floatx4;

__device__ __forceinline__ void async16(const void* g, void* l) {
    __builtin_amdgcn_global_load_lds((const __attribute__((address_space(1))) u32*)g,
                                     (__attribute__((address_space(3))) u32*)l, 16, 0, 0);
}
__device__ __forceinline__ unsigned short bf16rn(float f) {
    u32 u = __float_as_uint(f);
    return (unsigned short)((u + 0x7fffu + ((u >> 16) & 1u)) >> 16);
}

// ---------------- Threefry-2x32 (matches JAX rolled loop) ----------------
__device__ __forceinline__ void tf_round(unsigned &x0, unsigned &x1, int r) {
    x0 += x1;
    x1 = (x1 << r) | (x1 >> (32 - r));
    x1 ^= x0;
}
__device__ __forceinline__ void threefry(unsigned k0, unsigned k1,
                                         unsigned c0, unsigned c1,
                                         unsigned &o0, unsigned &o1) {
    unsigned ks0 = k0, ks1 = k1, ks2 = k0 ^ k1 ^ 0x1BD11BDAu;
    unsigned x0 = c0 + ks0, x1 = c1 + ks1;
    tf_round(x0,x1,13); tf_round(x0,x1,15); tf_round(x0,x1,26); tf_round(x0,x1,6);
    x0 += ks1; x1 += ks2 + 1u;
    tf_round(x0,x1,17); tf_round(x0,x1,29); tf_round(x0,x1,16); tf_round(x0,x1,24);
    x0 += ks2; x1 += ks0 + 2u;
    tf_round(x0,x1,13); tf_round(x0,x1,15); tf_round(x0,x1,26); tf_round(x0,x1,6);
    x0 += ks0; x1 += ks1 + 3u;
    tf_round(x0,x1,17); tf_round(x0,x1,29); tf_round(x0,x1,16); tf_round(x0,x1,24);
    x0 += ks1; x1 += ks2 + 4u;
    tf_round(x0,x1,13); tf_round(x0,x1,15); tf_round(x0,x1,26); tf_round(x0,x1,6);
    x0 += ks2; x1 += ks0 + 5u;
    o0 = x0; o1 = x1;
}

__global__ void sample_kernel(int* __restrict__ idx_sample) {
    const int HALF = (SEQ * NSAMP) / 2;  // 24576
    int p = blockIdx.x * blockDim.x + threadIdx.x;
    int li = blockIdx.y;
    if (p >= HALF) return;
    unsigned f0, f1;
    threefry(0u, 42u, 0u, (unsigned)li, f0, f1);          // fold_in
    unsigned a0, a1, b0, b1;
    threefry(f0, f1, 0u, 2u, a0, a1);                     // split
    threefry(f0, f1, 1u, 3u, b0, b1);
    unsigned o0, o1;
    threefry(a1, b1, (unsigned)p, (unsigned)(p + HALF), o0, o1);
    idx_sample[li * SEQ * NSAMP + p]        = (int)(o0 & (SEQ - 1));
    idx_sample[li * SEQ * NSAMP + p + HALF] = (int)(o1 & (SEQ - 1));
}

// ---------------- input layernorm over C_IN=32 ----------------
__global__ __launch_bounds__(256) void ln_in_kernel(const float* __restrict__ x,
        const float* __restrict__ g, const float* __restrict__ b,
        float* __restrict__ out) {
    int t = blockIdx.x * blockDim.x + threadIdx.x;
    if (t >= TOK) return;
    const float* xr = x + (size_t)t * CIN;
    float vals[CIN];
    float s = 0.f;
#pragma unroll
    for (int c = 0; c < CIN; c++) { vals[c] = xr[c]; s += vals[c]; }
    float m = s * (1.f / CIN);
    float v = 0.f;
#pragma unroll
    for (int c = 0; c < CIN; c++) { float d = vals[c] - m; v += d * d; }
    v *= (1.f / CIN);
    float inv = rsqrtf(v + EPS);
    float* orow = out + (size_t)t * CIN;
#pragma unroll
    for (int c = 0; c < CIN; c++) orow[c] = (vals[c] - m) * inv * g[c] + b[c];
}

// ---------------- token conv + pos emb + time emb ----------------
__global__ __launch_bounds__(256) void embed_kernel(const float* __restrict__ xln,
        const float* __restrict__ tfeat, const float* __restrict__ Wtok,
        const float* __restrict__ Wtime, const float* __restrict__ btime,
        float* __restrict__ h) {
    __shared__ float xs[96];
    __shared__ float tf4[4];
    int t = blockIdx.x;
    int b = t / SEQ, l = t % SEQ;
    int tid = threadIdx.x;
    if (tid < 96) {
        int w = tid / 32, c = tid % 32;
        int lw = (l - 1 + w + SEQ) % SEQ;  // wrap pad
        xs[tid] = xln[((size_t)b * SEQ + lw) * CIN + c];
    }
    if (tid < 4) tf4[tid] = tfeat[((size_t)b * SEQ + l) * 4 + tid];
    __syncthreads();
    const float c1 = -0.017988946039016f;  // -ln(10000)/512
    for (int o = tid; o < DM; o += 256) {
        float acc = btime[o];
        for (int j = 0; j < 96; j++) acc += xs[j] * Wtok[j * DM + o];
        acc += tf4[0] * Wtime[o * 4 + 0] + tf4[1] * Wtime[o * 4 + 1]
             + tf4[2] * Wtime[o * 4 + 2] + tf4[3] * Wtime[o * 4 + 3];
        int i2 = o & ~1;
        float div = expf((float)i2 * c1);
        float arg = (float)l * div;
        float pe = (o & 1) ? cosf(arg) : sinf(arg);
        h[(size_t)t * DM + o] = acc + pe;
    }
}

// ---------------- weight split: fp32 -> interleaved (bf16_h | bf16_l<<16) ----------------
__global__ __launch_bounds__(256) void split_weights(const float* __restrict__ Wq,
        const float* __restrict__ Wk, const float* __restrict__ Wv,
        const float* __restrict__ Wo, const float* __restrict__ W1,
        const float* __restrict__ W2, u32* __restrict__ out) {
    int i = blockIdx.x * 256 + threadIdx.x;  // < 3145728
    const float* src; int off;
    if (i < 1048576) {
        src = (i < 262144) ? Wq : (i < 524288) ? Wk : (i < 786432) ? Wv : Wo;
        off = i & 262143;
    } else if (i < 2097152) { src = W1; off = i - 1048576; }
    else { src = W2; off = i - 2097152; }
    float f = src[off];
    unsigned short h = bf16rn(f);
    unsigned short l = bf16rn(f - __uint_as_float((u32)h << 16));
    out[i] = (u32)h | ((u32)l << 16);
}

// ---------------- split-bf16 MFMA GEMM: C = A[MxK]*W[NxK]^T + bias (+res)(+relu) ----------
// A: fp32, split on the fly.  Wp: interleaved (h|l<<16) uint32.
template<bool RELU, bool RES>
__global__ __launch_bounds__(256, 2) void gemm_split(const float* __restrict__ A,
        const u32* __restrict__ Wp, const float* __restrict__ bias,
        const float* __restrict__ Rsd, float* __restrict__ C,
        int N, int K, int lda) {
    __shared__ alignas(16) unsigned short AhS[128 * 40];   // padded stride 40
    __shared__ alignas(16) unsigned short AlS[128 * 40];
    __shared__ alignas(16) u32 Wt[4 * 128 * 8];            // [kchunk8][row][8 words]
    const int tid = threadIdx.x;
    const int m0 = blockIdx.y * 128, n0 = blockIdx.x * 128;
    const int lane = tid & 63, wv = tid >> 6;
    const int wm = wv >> 1, wn = wv & 1;
    const int fr = lane & 15, q = lane >> 4;

    floatx4 acc[4][4] = {};

    const int arow = tid >> 1, ahalf = tid & 1;
    const float* abase = A + (size_t)(m0 + arow) * lda + ahalf * 16;
    const u32* wbase = Wp + (size_t)(n0 + (tid >> 1)) * K + (tid & 1) * 4;
    char* wdst = (char*)Wt + tid * 16;
    unsigned short* ahw = &AhS[arow * 40 + ahalf * 16];
    unsigned short* alw = &AlS[arow * 40 + ahalf * 16];

    for (int k0 = 0; k0 < K; k0 += 32) {
        // --- stage W tile (async DMA to LDS, chunked 8-elem layout) ---
#pragma unroll
        for (int i = 0; i < 4; i++)
            async16(wbase + k0 + i * 8, wdst + i * 4096);
        // --- stage A tile: fp32 load, split to bf16 h/l, LDS write ---
        const float* ap = abase + k0;
        float f[16];
        *(float4*)&f[0]  = *(const float4*)(ap);
        *(float4*)&f[4]  = *(const float4*)(ap + 4);
        *(float4*)&f[8]  = *(const float4*)(ap + 8);
        *(float4*)&f[12] = *(const float4*)(ap + 12);
        short8 h0, h1, l0, l1;
#pragma unroll
        for (int j = 0; j < 8; j++) {
            unsigned short hb = bf16rn(f[j]);
            float r = f[j] - __uint_as_float((u32)hb << 16);
            h0[j] = (short)hb; l0[j] = (short)bf16rn(r);
            unsigned short hb2 = bf16rn(f[j + 8]);
            float r2 = f[j + 8] - __uint_as_float((u32)hb2 << 16);
            h1[j] = (short)hb2; l1[j] = (short)bf16rn(r2);
        }
        *(short8*)(ahw)     = h0;  *(short8*)(ahw + 8) = h1;
        *(short8*)(alw)     = l0;  *(short8*)(alw + 8) = l1;
        __syncthreads();
        // --- fragments + MFMA ---
        short8 ah[4], al[4];
#pragma unroll
        for (int mi = 0; mi < 4; mi++) {
            int off = (wm * 64 + mi * 16 + fr) * 40 + q * 8;
            ah[mi] = *(const short8*)&AhS[off];
            al[mi] = *(const short8*)&AlS[off];
        }
#pragma unroll
        for (int ni = 0; ni < 4; ni++) {
            const u32* cell = &Wt[(size_t)(q * 128 + wn * 64 + ni * 16 + fr) * 8];
            union { u32 u[4]; short8 s; } wh, wl;
            u32 w0 = cell[0], w1 = cell[1], w2 = cell[2], w3 = cell[3];
            u32 w4 = cell[4], w5 = cell[5], w6 = cell[6], w7 = cell[7];
            wh.u[0] = (w0 & 0xffffu) | (w1 << 16);
            wh.u[1] = (w2 & 0xffffu) | (w3 << 16);
            wh.u[2] = (w4 & 0xffffu) | (w5 << 16);
            wh.u[3] = (w6 & 0xffffu) | (w7 << 16);
            wl.u[0] = (w0 >> 16) | (w1 & 0xffff0000u);
            wl.u[1] = (w2 >> 16) | (w3 & 0xffff0000u);
            wl.u[2] = (w4 >> 16) | (w5 & 0xffff0000u);
            wl.u[3] = (w6 >> 16) | (w7 & 0xffff0000u);
#pragma unroll
            for (int mi = 0; mi < 4; mi++) {
                acc[mi][ni] = __builtin_amdgcn_mfma_f32_16x16x32_bf16(ah[mi], wh.s, acc[mi][ni], 0, 0, 0);
                acc[mi][ni] = __builtin_amdgcn_mfma_f32_16x16x32_bf16(ah[mi], wl.s, acc[mi][ni], 0, 0, 0);
                acc[mi][ni] = __builtin_amdgcn_mfma_f32_16x16x32_bf16(al[mi], wh.s, acc[mi][ni], 0, 0, 0);
            }
        }
        __syncthreads();
    }
    // --- epilogue ---
#pragma unroll
    for (int ni = 0; ni < 4; ni++) {
        int col = n0 + wn * 64 + ni * 16 + fr;
        float bv = bias[col];
#pragma unroll
        for (int mi = 0; mi < 4; mi++) {
            int row = m0 + wm * 64 + mi * 16 + q * 4;
#pragma unroll
            for (int r = 0; r < 4; r++) {
                size_t idx = (size_t)(row + r) * N + col;
                float v = acc[mi][ni][r] + bv;
                if (RES) v += Rsd[idx];
                if (RELU) v = fmaxf(v, 0.f);
                C[idx] = v;
            }
        }
    }
}

// ---------------- M = max(QK_sample) - sum(QK_sample)/L : one wave per (b,h,l) ----------------
__global__ __launch_bounds__(256) void qk_sample_kernel(const float* __restrict__ q,
        const float* __restrict__ k, const int* __restrict__ idx_sample,
        float* __restrict__ Mout) {
    int r = (blockIdx.x * 256 + threadIdx.x) / 64;
    int lane = threadIdx.x & 63;
    if (r >= BATCH * NH * SEQ) return;
    int b = r / (NH * SEQ);
    int head = (r / SEQ) % NH;
    int l = r % SEQ;
    float qd = q[((size_t)(b * SEQ + l)) * DM + head * HD + lane];
    float mx = -INFINITY, sm = 0.f;
    for (int s = 0; s < NSAMP; s++) {
        int idx = idx_sample[l * NSAMP + s];
        float kd = k[((size_t)(b * SEQ + idx)) * DM + head * HD + lane];
        float p = qd * kd;
#pragma unroll
        for (int off = 32; off > 0; off >>= 1) p += __shfl_xor(p, off);
        mx = fmaxf(mx, p);
        sm += p;
    }
    if (lane == 0) Mout[r] = mx - sm * (1.f / SEQ);
}

// ---------------- top-24 (stable, ties -> lower index) per (b,h) ----------------
__global__ __launch_bounds__(256) void topk_kernel(const float* __restrict__ Mbuf,
        int* __restrict__ idx_top) {
    __shared__ float vals[SEQ];
    __shared__ float rv[256];
    __shared__ int   ri[256];
    int bh = blockIdx.x;
    int tid = threadIdx.x;
    const float* Mr = Mbuf + (size_t)bh * SEQ;
    for (int i = tid; i < SEQ; i += 256) vals[i] = Mr[i];
    __syncthreads();
    for (int it = 0; it < NTOP; it++) {
        float best = -INFINITY; int bi = SEQ;
        for (int i = tid; i < SEQ; i += 256) {
            float v = vals[i];
            if (v > best || (v == best && i < bi)) { best = v; bi = i; }
        }
        rv[tid] = best; ri[tid] = bi;
        __syncthreads();
        for (int s = 128; s > 0; s >>= 1) {
            if (tid < s) {
                float v2 = rv[tid + s]; int i2 = ri[tid + s];
                if (v2 > rv[tid] || (v2 == rv[tid] && i2 < ri[tid])) { rv[tid] = v2; ri[tid] = i2; }
            }
            __syncthreads();
        }
        if (tid == 0) { idx_top[bh * NTOP + it] = ri[0]; vals[ri[0]] = -INFINITY; }
        __syncthreads();
    }
}

// ---------------- V mean over keys per (b,h): parallel partial + atomics ----------------
__global__ __launch_bounds__(256) void vmean_kernel(const float* __restrict__ v,
        float* __restrict__ vmean) {
    __shared__ float red[256];
    int bh = blockIdx.x, slab = blockIdx.y;
    int b = bh >> 3, head = bh & 7;
    int seg = threadIdx.x >> 6, d = threadIdx.x & 63;
    int base_row = slab * 256 + seg * 64;
    float s = 0.f;
    for (int r = 0; r < 64; r++)
        s += v[((size_t)(b * SEQ + base_row + r)) * DM + head * HD + d];
    red[threadIdx.x] = s;
    __syncthreads();
    if (threadIdx.x < 128) red[threadIdx.x] += red[threadIdx.x + 128];
    __syncthreads();
    if (threadIdx.x < 64) {
        float t = red[threadIdx.x] + red[threadIdx.x + 64];
        atomicAdd(&vmean[bh * HD + d], t * (1.f / SEQ));
    }
}

// ---------------- fill context with V-mean ----------------
__global__ void fillctx_kernel(const float* __restrict__ vmean, float* __restrict__ out) {
    int e = blockIdx.x * 256 + threadIdx.x;  // < TOK*DM
    int c = e % DM;
    int b = e / (SEQ * DM);
    out[e] = vmean[(b * NH + (c / HD)) * HD + (c % HD)];
}

// ---------------- full attention for the 24 selected queries ----------------
__global__ __launch_bounds__(256) void spattn_kernel(const float* __restrict__ q,
        const float* __restrict__ k, const float* __restrict__ v,
        const int* __restrict__ idx_top, float* __restrict__ out) {
    __shared__ float qrow[HD];
    __shared__ float sc[SEQ];
    __shared__ float red[256];
    int blk = blockIdx.x;
    int u = blk % NTOP;
    int bh = blk / NTOP;
    int head = bh % NH, b = bh / NH;
    int tid = threadIdx.x;
    int qi = idx_top[bh * NTOP + u];
    if (tid < HD) qrow[tid] = q[((size_t)(b * SEQ + qi)) * DM + head * HD + tid];
    __syncthreads();
    for (int kk = tid; kk < SEQ; kk += 256) {
        const float* kr = k + ((size_t)(b * SEQ + kk)) * DM + head * HD;
        float dot = 0.f;
#pragma unroll
        for (int d = 0; d < HD; d += 4) {
            float4 k4 = *(const float4*)&kr[d];
            dot += qrow[d] * k4.x + qrow[d + 1] * k4.y + qrow[d + 2] * k4.z + qrow[d + 3] * k4.w;
        }
        sc[kk] = dot * 0.125f;
    }
    __syncthreads();
    float lm = -INFINITY;
    for (int kk = tid; kk < SEQ; kk += 256) lm = fmaxf(lm, sc[kk]);
    red[tid] = lm; __syncthreads();
    for (int s = 128; s > 0; s >>= 1) { if (tid < s) red[tid] = fmaxf(red[tid], red[tid + s]); __syncthreads(); }
    float mx = red[0];
    __syncthreads();
    float ls = 0.f;
    for (int kk = tid; kk < SEQ; kk += 256) { float e = expf(sc[kk] - mx); sc[kk] = e; ls += e; }
    red[tid] = ls; __syncthreads();
    for (int s = 128; s > 0; s >>= 1) { if (tid < s) red[tid] += red[tid + s]; __syncthreads(); }
    float ssum = red[0];
    __syncthreads();
    int d = tid % HD, seg = tid / HD;
    float pa = 0.f;
    for (int kk = seg * 512; kk < (seg + 1) * 512; kk++)
        pa += sc[kk] * v[((size_t)(b * SEQ + kk)) * DM + head * HD + d];
    red[tid] = pa; __syncthreads();
    if (tid < HD) {
        float upd = (red[tid] + red[tid + 64] + red[tid + 128] + red[tid + 192]) / ssum;
        out[((size_t)(b * SEQ + qi)) * DM + head * HD + tid] = upd;
    }
}

// ---------------- layernorm over DM=512 ----------------
__global__ __launch_bounds__(256) void ln_kernel(const float* src,
        const float* __restrict__ g, const float* __restrict__ b, float* dst) {
    __shared__ float red[256];
    int t = blockIdx.x, tid = threadIdx.x;
    const float* xr = src + (size_t)t * DM;
    float x0 = xr[tid], x1 = xr[tid + 256];
    red[tid] = x0 + x1; __syncthreads();
    for (int s = 128; s > 0; s >>= 1) { if (tid < s) red[tid] += red[tid + s]; __syncthreads(); }
    float m = red[0] * (1.f / DM);
    __syncthreads();
    float d0 = x0 - m, d1 = x1 - m;
    red[tid] = d0 * d0 + d1 * d1; __syncthreads();
    for (int s = 128; s > 0; s >>= 1) { if (tid < s) red[tid] += red[tid + s]; __syncthreads(); }
    float inv = rsqrtf(red[0] * (1.f / DM) + EPS);
    float* dr = dst + (size_t)t * DM;
    dr[tid] = d0 * inv * g[tid] + b[tid];
    dr[tid + 256] = d1 * inv * g[tid + 256] + b[tid + 256];
}

// ---------------- prediction head on last token ----------------
__global__ __launch_bounds__(256) void head_kernel(const float* __restrict__ hfin,
        const float* __restrict__ Wpre, const float* __restrict__ bpre,
        const float* __restrict__ Wfc, const float* __restrict__ bfc,
        float* __restrict__ out) {
    __shared__ float last[DM];
    __shared__ float red[256];
    int b = blockIdx.x, tid = threadIdx.x;
    const float* hr = hfin + ((size_t)(b * SEQ + SEQ - 1)) * DM;
    last[tid] = hr[tid];
    last[tid + 256] = hr[tid + 256];
    __syncthreads();
    float acc = bpre[tid];
    for (int c = 0; c < DM; c++) acc += last[c] * Wpre[tid * DM + c];
    acc = fmaxf(acc, 0.f);
    red[tid] = acc * Wfc[tid];
    __syncthreads();
    for (int s = 128; s > 0; s >>= 1) { if (tid < s) red[tid] += red[tid + s]; __syncthreads(); }
    if (tid == 0) out[b] = red[0] + bfc[0];
}

extern "C" void kernel_launch(void* const* d_in, const int* in_sizes, int n_in,
                              void* d_out, int out_size, void* d_ws, size_t ws_size,
                              hipStream_t stream) {
    (void)in_sizes; (void)n_in; (void)out_size; (void)ws_size;
    const float* x      = (const float*)d_in[0];
    const float* tfeat  = (const float*)d_in[1];
    const float* g_in   = (const float*)d_in[2];
    const float* b_in   = (const float*)d_in[3];
    const float* W_tok  = (const float*)d_in[4];
    const float* W_time = (const float*)d_in[5];
    const float* b_time = (const float*)d_in[6];
    const float* Wq     = (const float*)d_in[7];
    const float* bq     = (const float*)d_in[8];
    const float* Wk     = (const float*)d_in[9];
    const float* bk     = (const float*)d_in[10];
    const float* Wv     = (const float*)d_in[11];
    const float* bv     = (const float*)d_in[12];
    const float* Wo     = (const float*)d_in[13];
    const float* bo     = (const float*)d_in[14];
    const float* W1     = (const float*)d_in[15];
    const float* b1     = (const float*)d_in[16];
    const float* W2     = (const float*)d_in[17];
    const float* b2     = (const float*)d_in[18];
    const float* g1     = (const float*)d_in[19];
    const float* be1    = (const float*)d_in[20];
    const float* g2     = (const float*)d_in[21];
    const float* be2    = (const float*)d_in[22];
    const float* g_enc  = (const float*)d_in[23];
    const float* b_enc  = (const float*)d_in[24];
    const float* W_pre  = (const float*)d_in[25];
    const float* b_pre  = (const float*)d_in[26];
    const float* W_fc   = (const float*)d_in[27];
    const float* b_fc   = (const float*)d_in[28];
    float* out = (float*)d_out;

    char* ws = (char*)d_ws;
    float* h    = (float*)(ws);                      // 33.5 MB
    float* tmp  = (float*)(ws + 33554432);           // 33.5 MB
    float* big  = (float*)(ws + 67108864);           // 134.2 MB: q,k,v fp32 OR ffn mid fp32
    float* qb = big;
    float* kb = big + 8388608;
    float* vb = big + 16777216;
    u32*   wpair      = (u32*)(ws + 201326592);      // 12.6 MB (per-layer split weights)
    float* xln        = (float*)(ws + 213909504);    // 2 MB
    float* Mbuf       = (float*)(ws + 216006656);    // 0.5 MB
    float* vmean      = (float*)(ws + 216530944);    // 16 KB
    int*   idx_sample = (int*)(ws + 216547328);      // 384 KB
    int*   idx_top    = (int*)(ws + 216940544);      // 6 KB

    ln_in_kernel<<<TOK / 256, 256, 0, stream>>>(x, g_in, b_in, xln);
    embed_kernel<<<TOK, 256, 0, stream>>>(xln, tfeat, W_tok, W_time, b_time, h);
    sample_kernel<<<dim3(96, 2), 256, 0, stream>>>(idx_sample);

    const u32* wq_p = wpair;
    const u32* wk_p = wpair + 262144;
    const u32* wv_p = wpair + 524288;
    const u32* wo_p = wpair + 786432;
    const u32* w1_p = wpair + 1048576;
    const u32* w2_p = wpair + 2097152;

    for (int li = 0; li < 2; li++) {
        split_weights<<<12288, 256, 0, stream>>>(
            Wq + (size_t)li * DM * DM, Wk + (size_t)li * DM * DM,
            Wv + (size_t)li * DM * DM, Wo + (size_t)li * DM * DM,
            W1 + (size_t)li * DFF * DM, W2 + (size_t)li * DM * DFF, wpair);

        const float* bq_i = bq + (size_t)li * DM;
        const float* bk_i = bk + (size_t)li * DM;
        const float* bv_i = bv + (size_t)li * DM;
        const float* bo_i = bo + (size_t)li * DM;
        const float* b1_i = b1 + (size_t)li * DFF;
        const float* b2_i = b2 + (size_t)li * DM;
        const float* g1_i = g1 + (size_t)li * DM;
        const float* be1_i = be1 + (size_t)li * DM;
        const float* g2_i = g2 + (size_t)li * DM;
        const float* be2_i = be2 + (size_t)li * DM;

        dim3 gQ(DM / 128, TOK / 128);      // (4, 128)
        gemm_split<false, false><<<gQ, 256, 0, stream>>>(h, wq_p, bq_i, nullptr, qb, DM, DM, DM);
        gemm_split<false, false><<<gQ, 256, 0, stream>>>(h, wk_p, bk_i, nullptr, kb, DM, DM, DM);
        gemm_split<false, false><<<gQ, 256, 0, stream>>>(h, wv_p, bv_i, nullptr, vb, DM, DM, DM);

        qk_sample_kernel<<<(BATCH * NH * SEQ) / 4, 256, 0, stream>>>(
            qb, kb, idx_sample + li * SEQ * NSAMP, Mbuf);
        topk_kernel<<<BATCH * NH, 256, 0, stream>>>(Mbuf, idx_top);
        hipMemsetAsync(vmean, 0, BATCH * NH * HD * sizeof(float), stream);
        vmean_kernel<<<dim3(BATCH * NH, 8), 256, 0, stream>>>(vb, vmean);
        fillctx_kernel<<<(TOK * DM) / 256, 256, 0, stream>>>(vmean, tmp);
        spattn_kernel<<<BATCH * NH * NTOP, 256, 0, stream>>>(qb, kb, vb, idx_top, tmp);

        gemm_split<false, true><<<gQ, 256, 0, stream>>>(tmp, wo_p, bo_i, h, h, DM, DM, DM);
        ln_kernel<<<TOK, 256, 0, stream>>>(h, g1_i, be1_i, h);

        gemm_split<true, false><<<dim3(DFF / 128, TOK / 128), 256, 0, stream>>>(
            h, w1_p, b1_i, nullptr, big, DFF, DM, DM);
        gemm_split<false, true><<<dim3(DM / 128, TOK / 128), 256, 0, stream>>>(
            big, w2_p, b2_i, h, tmp, DM, DFF, DFF);
        ln_kernel<<<TOK, 256, 0, stream>>>(tmp, g2_i, be2_i, h);
    }

    ln_kernel<<<TOK, 256, 0, stream>>>(h, g_enc, b_enc, tmp);
    head_kernel<<<BATCH, 256, 0, stream>>>(tmp, W_pre, b_pre, W_fc, b_fc, out);
}

// Round 3
// 1814.078 us; speedup vs baseline: 2.5319x; 1.4272x over previous
//
#include <hip/hip_runtime.h>
#include <math.h>

#define BATCH 8
#define SEQ   2048
#define TOK   (BATCH*SEQ)     // 16384
#define CIN   32
#define DM    512
#define DFF   2048
#define NH    8
#define HD    64
#define NSAMP 24
#define NTOP  24
#define EPS   1e-5f
#define QKVLD 1536

typedef unsigned int u32;
typedef unsigned short u16;
typedef __attribute__((ext_vector_type(8))) short short8;
typedef __attribute__((ext_vector_type(4))) float floatx4;

__device__ __forceinline__ void async16(const void* g, void* l) {
    __builtin_amdgcn_global_load_lds((const __attribute__((address_space(1))) u32*)g,
                                     (__attribute__((address_space(3))) u32*)l, 16, 0, 0);
}
__device__ __forceinline__ u16 bf16rn(float f) {
    u32 u = __float_as_uint(f);
    return (u16)((u + 0x7fffu + ((u >> 16) & 1u)) >> 16);
}

// ---------------- Threefry-2x32 ----------------
__device__ __forceinline__ void tf_round(unsigned &x0, unsigned &x1, int r) {
    x0 += x1;
    x1 = (x1 << r) | (x1 >> (32 - r));
    x1 ^= x0;
}
__device__ __forceinline__ void threefry(unsigned k0, unsigned k1,
                                         unsigned c0, unsigned c1,
                                         unsigned &o0, unsigned &o1) {
    unsigned ks0 = k0, ks1 = k1, ks2 = k0 ^ k1 ^ 0x1BD11BDAu;
    unsigned x0 = c0 + ks0, x1 = c1 + ks1;
    tf_round(x0,x1,13); tf_round(x0,x1,15); tf_round(x0,x1,26); tf_round(x0,x1,6);
    x0 += ks1; x1 += ks2 + 1u;
    tf_round(x0,x1,17); tf_round(x0,x1,29); tf_round(x0,x1,16); tf_round(x0,x1,24);
    x0 += ks2; x1 += ks0 + 2u;
    tf_round(x0,x1,13); tf_round(x0,x1,15); tf_round(x0,x1,26); tf_round(x0,x1,6);
    x0 += ks0; x1 += ks1 + 3u;
    tf_round(x0,x1,17); tf_round(x0,x1,29); tf_round(x0,x1,16); tf_round(x0,x1,24);
    x0 += ks1; x1 += ks2 + 4u;
    tf_round(x0,x1,13); tf_round(x0,x1,15); tf_round(x0,x1,26); tf_round(x0,x1,6);
    x0 += ks2; x1 += ks0 + 5u;
    o0 = x0; o1 = x1;
}

__global__ void sample_kernel(int* __restrict__ idx_sample) {
    const int HALF = (SEQ * NSAMP) / 2;  // 24576
    int p = blockIdx.x * blockDim.x + threadIdx.x;
    int li = blockIdx.y;
    if (p >= HALF) return;
    unsigned f0, f1;
    threefry(0u, 42u, 0u, (unsigned)li, f0, f1);
    unsigned a0, a1, b0, b1;
    threefry(f0, f1, 0u, 2u, a0, a1);
    threefry(f0, f1, 1u, 3u, b0, b1);
    unsigned o0, o1;
    threefry(a1, b1, (unsigned)p, (unsigned)(p + HALF), o0, o1);
    idx_sample[li * SEQ * NSAMP + p]        = (int)(o0 & (SEQ - 1));
    idx_sample[li * SEQ * NSAMP + p + HALF] = (int)(o1 & (SEQ - 1));
}

// ---------------- input layernorm over C_IN=32 ----------------
__global__ __launch_bounds__(256) void ln_in_kernel(const float* __restrict__ x,
        const float* __restrict__ g, const float* __restrict__ b,
        float* __restrict__ out) {
    int t = blockIdx.x * blockDim.x + threadIdx.x;
    if (t >= TOK) return;
    const float* xr = x + (size_t)t * CIN;
    float vals[CIN];
    float s = 0.f;
#pragma unroll
    for (int c = 0; c < CIN; c++) { vals[c] = xr[c]; s += vals[c]; }
    float m = s * (1.f / CIN);
    float v = 0.f;
#pragma unroll
    for (int c = 0; c < CIN; c++) { float d = vals[c] - m; v += d * d; }
    v *= (1.f / CIN);
    float inv = rsqrtf(v + EPS);
    float* orow = out + (size_t)t * CIN;
#pragma unroll
    for (int c = 0; c < CIN; c++) orow[c] = (vals[c] - m) * inv * g[c] + b[c];
}

// ---------------- token conv + pos emb + time emb ----------------
__global__ __launch_bounds__(256) void embed_kernel(const float* __restrict__ xln,
        const float* __restrict__ tfeat, const float* __restrict__ Wtok,
        const float* __restrict__ Wtime, const float* __restrict__ btime,
        float* __restrict__ h) {
    __shared__ float xs[96];
    __shared__ float tf4[4];
    int t = blockIdx.x;
    int b = t / SEQ, l = t % SEQ;
    int tid = threadIdx.x;
    if (tid < 96) {
        int w = tid / 32, c = tid % 32;
        int lw = (l - 1 + w + SEQ) % SEQ;
        xs[tid] = xln[((size_t)b * SEQ + lw) * CIN + c];
    }
    if (tid < 4) tf4[tid] = tfeat[((size_t)b * SEQ + l) * 4 + tid];
    __syncthreads();
    const float c1 = -0.017988946039016f;  // -ln(10000)/512
    for (int o = tid; o < DM; o += 256) {
        float acc = btime[o];
        for (int j = 0; j < 96; j++) acc += xs[j] * Wtok[j * DM + o];
        acc += tf4[0] * Wtime[o * 4 + 0] + tf4[1] * Wtime[o * 4 + 1]
             + tf4[2] * Wtime[o * 4 + 2] + tf4[3] * Wtime[o * 4 + 3];
        int i2 = o & ~1;
        float div = expf((float)i2 * c1);
        float arg = (float)l * div;
        float pe = (o & 1) ? cosf(arg) : sinf(arg);
        h[(size_t)t * DM + o] = acc + pe;
    }
}

// ---------------- weight split: fp32 -> separate bf16 high/low buffers ----------------
__global__ __launch_bounds__(256) void split_weights(const float* __restrict__ Wq,
        const float* __restrict__ Wk, const float* __restrict__ Wv,
        const float* __restrict__ Wo, const float* __restrict__ W1,
        const float* __restrict__ W2, u16* __restrict__ wh, u16* __restrict__ wl) {
    int i = blockIdx.x * 256 + threadIdx.x;  // < 3145728
    const float* src; int off;
    if (i < 1048576) {
        src = (i < 262144) ? Wq : (i < 524288) ? Wk : (i < 786432) ? Wv : Wo;
        off = i & 262143;
    } else if (i < 2097152) { src = W1; off = i - 1048576; }
    else { src = W2; off = i - 2097152; }
    float f = src[off];
    u16 h = bf16rn(f);
    u16 l = bf16rn(f - __uint_as_float((u32)h << 16));
    wh[i] = h;
    wl[i] = l;
}

__global__ void concat_bias(const float* __restrict__ bq, const float* __restrict__ bk,
                            const float* __restrict__ bv, float* __restrict__ o) {
    int i = blockIdx.x * 256 + threadIdx.x;  // < 1536
    o[i] = (i < 512) ? bq[i] : (i < 1024) ? bk[i - 512] : bv[i - 1024];
}

// ---------------- split-bf16 MFMA GEMM: C = A[MxK]*W[NxK]^T + bias (+res)(+relu) ----------
template<bool RELU, bool RES>
__global__ __launch_bounds__(256, 2) void gemm_split(const float* __restrict__ A,
        const u16* __restrict__ Wh, const u16* __restrict__ Wl,
        const float* __restrict__ bias, const float* __restrict__ Rsd,
        float* __restrict__ C, int ldc, int K, int lda) {
    __shared__ alignas(16) u16 AhS[128 * 40];     // padded stride 40
    __shared__ alignas(16) u16 AlS[128 * 40];
    __shared__ alignas(16) u16 WhS[4 * 128 * 8];  // [kchunk][row][8] bf16
    __shared__ alignas(16) u16 WlS[4 * 128 * 8];
    const int tid = threadIdx.x;
    const int m0 = blockIdx.y * 128, n0 = blockIdx.x * 128;
    const int lane = tid & 63, wv = tid >> 6;
    const int wm = wv >> 1, wn = wv & 1;
    const int fr = lane & 15, q = lane >> 4;

    floatx4 acc[4][4] = {};

    const int arow = tid >> 1, ahalf = tid & 1;
    const float* abase = A + (size_t)(m0 + arow) * lda + ahalf * 16;
    const int wrow = tid & 127, wc0 = tid >> 7;
    const u16* whbase = Wh + (size_t)(n0 + wrow) * K + wc0 * 8;
    const u16* wlbase = Wl + (size_t)(n0 + wrow) * K + wc0 * 8;
    char* whdst = (char*)WhS + tid * 16;
    char* wldst = (char*)WlS + tid * 16;
    u16* ahw = &AhS[arow * 40 + ahalf * 16];
    u16* alw = &AlS[arow * 40 + ahalf * 16];

    for (int k0 = 0; k0 < K; k0 += 32) {
        // --- stage W tiles (async DMA, fragment-layout chunks: chunk c holds k=c*8..c*8+7) ---
#pragma unroll
        for (int i = 0; i < 2; i++) {
            async16(whbase + k0 + i * 16, whdst + i * 4096);
            async16(wlbase + k0 + i * 16, wldst + i * 4096);
        }
        // --- stage A tile: fp32 load, split to bf16 h/l ---
        const float* ap = abase + k0;
        float f[16];
        *(float4*)&f[0]  = *(const float4*)(ap);
        *(float4*)&f[4]  = *(const float4*)(ap + 4);
        *(float4*)&f[8]  = *(const float4*)(ap + 8);
        *(float4*)&f[12] = *(const float4*)(ap + 12);
        short8 h0, h1, l0, l1;
#pragma unroll
        for (int j = 0; j < 8; j++) {
            u16 hb = bf16rn(f[j]);
            float r = f[j] - __uint_as_float((u32)hb << 16);
            h0[j] = (short)hb; l0[j] = (short)bf16rn(r);
            u16 hb2 = bf16rn(f[j + 8]);
            float r2 = f[j + 8] - __uint_as_float((u32)hb2 << 16);
            h1[j] = (short)hb2; l1[j] = (short)bf16rn(r2);
        }
        *(short8*)(ahw)     = h0;  *(short8*)(ahw + 8) = h1;
        *(short8*)(alw)     = l0;  *(short8*)(alw + 8) = l1;
        __syncthreads();
        // --- fragments + MFMA ---
        short8 ah[4], al[4];
#pragma unroll
        for (int mi = 0; mi < 4; mi++) {
            int off = (wm * 64 + mi * 16 + fr) * 40 + q * 8;
            ah[mi] = *(const short8*)&AhS[off];
            al[mi] = *(const short8*)&AlS[off];
        }
#pragma unroll
        for (int ni = 0; ni < 4; ni++) {
            int woff = (q * 128 + wn * 64 + ni * 16 + fr) * 8;
            short8 wh8 = *(const short8*)&WhS[woff];
            short8 wl8 = *(const short8*)&WlS[woff];
#pragma unroll
            for (int mi = 0; mi < 4; mi++) {
                acc[mi][ni] = __builtin_amdgcn_mfma_f32_16x16x32_bf16(ah[mi], wh8, acc[mi][ni], 0, 0, 0);
                acc[mi][ni] = __builtin_amdgcn_mfma_f32_16x16x32_bf16(ah[mi], wl8, acc[mi][ni], 0, 0, 0);
                acc[mi][ni] = __builtin_amdgcn_mfma_f32_16x16x32_bf16(al[mi], wh8, acc[mi][ni], 0, 0, 0);
            }
        }
        __syncthreads();
    }
    // --- epilogue ---
#pragma unroll
    for (int ni = 0; ni < 4; ni++) {
        int col = n0 + wn * 64 + ni * 16 + fr;
        float bv = bias[col];
#pragma unroll
        for (int mi = 0; mi < 4; mi++) {
            int row = m0 + wm * 64 + mi * 16 + q * 4;
#pragma unroll
            for (int r = 0; r < 4; r++) {
                size_t idx = (size_t)(row + r) * ldc + col;
                float v = acc[mi][ni][r] + bv;
                if (RES) v += Rsd[idx];
                if (RELU) v = fmaxf(v, 0.f);
                C[idx] = v;
            }
        }
    }
}

// ---------------- M = max(QK_sample) - sum/L : one wave per (b,h,l), qkv packed ----------------
__global__ __launch_bounds__(256) void qk_sample_kernel(const float* __restrict__ qkv,
        const int* __restrict__ idx_sample, float* __restrict__ Mout) {
    int r = (blockIdx.x * 256 + threadIdx.x) / 64;
    int lane = threadIdx.x & 63;
    if (r >= BATCH * NH * SEQ) return;
    int b = r / (NH * SEQ);
    int head = (r / SEQ) % NH;
    int l = r % SEQ;
    float qd = qkv[((size_t)(b * SEQ + l)) * QKVLD + head * HD + lane];
    int idxs[NSAMP];
#pragma unroll
    for (int s = 0; s < NSAMP; s++) idxs[s] = idx_sample[l * NSAMP + s];
    float kd[NSAMP];
#pragma unroll
    for (int s = 0; s < NSAMP; s++)
        kd[s] = qkv[((size_t)(b * SEQ + idxs[s])) * QKVLD + 512 + head * HD + lane];
    float mx = -INFINITY, sm = 0.f;
#pragma unroll
    for (int s = 0; s < NSAMP; s++) {
        float p = qd * kd[s];
#pragma unroll
        for (int off = 32; off > 0; off >>= 1) p += __shfl_xor(p, off);
        mx = fmaxf(mx, p);
        sm += p;
    }
    if (lane == 0) Mout[r] = mx - sm * (1.f / SEQ);
}

// ---------------- top-24 (stable, ties -> lower index) per (b,h) ----------------
__global__ __launch_bounds__(256) void topk_kernel(const float* __restrict__ Mbuf,
        int* __restrict__ idx_top) {
    __shared__ float vals[SEQ];
    __shared__ float rv[256];
    __shared__ int   ri[256];
    int bh = blockIdx.x;
    int tid = threadIdx.x;
    const float* Mr = Mbuf + (size_t)bh * SEQ;
    for (int i = tid; i < SEQ; i += 256) vals[i] = Mr[i];
    __syncthreads();
    for (int it = 0; it < NTOP; it++) {
        float best = -INFINITY; int bi = SEQ;
        for (int i = tid; i < SEQ; i += 256) {
            float v = vals[i];
            if (v > best || (v == best && i < bi)) { best = v; bi = i; }
        }
        rv[tid] = best; ri[tid] = bi;
        __syncthreads();
        for (int s = 128; s > 0; s >>= 1) {
            if (tid < s) {
                float v2 = rv[tid + s]; int i2 = ri[tid + s];
                if (v2 > rv[tid] || (v2 == rv[tid] && i2 < ri[tid])) { rv[tid] = v2; ri[tid] = i2; }
            }
            __syncthreads();
        }
        if (tid == 0) { idx_top[bh * NTOP + it] = ri[0]; vals[ri[0]] = -INFINITY; }
        __syncthreads();
    }
}

// ---------------- V mean over keys per (b,h) ----------------
__global__ __launch_bounds__(256) void vmean_kernel(const float* __restrict__ qkv,
        float* __restrict__ vmean) {
    __shared__ float red[256];
    int bh = blockIdx.x, slab = blockIdx.y;
    int b = bh >> 3, head = bh & 7;
    int seg = threadIdx.x >> 6, d = threadIdx.x & 63;
    int base_row = slab * 256 + seg * 64;
    float s = 0.f;
    for (int r = 0; r < 64; r++)
        s += qkv[((size_t)(b * SEQ + base_row + r)) * QKVLD + 1024 + head * HD + d];
    red[threadIdx.x] = s;
    __syncthreads();
    if (threadIdx.x < 128) red[threadIdx.x] += red[threadIdx.x + 128];
    __syncthreads();
    if (threadIdx.x < 64) {
        float t = red[threadIdx.x] + red[threadIdx.x + 64];
        atomicAdd(&vmean[bh * HD + d], t * (1.f / SEQ));
    }
}

// ---------------- fill context with V-mean ----------------
__global__ void fillctx_kernel(const float* __restrict__ vmean, float* __restrict__ out) {
    int e = blockIdx.x * 256 + threadIdx.x;
    int c = e % DM;
    int b = e / (SEQ * DM);
    out[e] = vmean[(b * NH + (c / HD)) * HD + (c % HD)];
}

// ---------------- flash-style sparse attention: block = (b*h, key-slab of 512) ----------------
__global__ __launch_bounds__(256) void spattn_flash(const float* __restrict__ qkv,
        const int* __restrict__ idx_top, float* __restrict__ opart,
        float* __restrict__ mspart) {
    __shared__ float KtT[64][65];   // transposed: [dim][key]
    __shared__ float Vt[64][65];    // [key][dim]
    __shared__ float Qs[24][64];
    __shared__ float Ps[24][66];
    int bh = blockIdx.x, slab = blockIdx.y;
    int b = bh >> 3, h = bh & 7;
    int tid = threadIdx.x;
    int wv = tid >> 6, lane = tid & 63;
    // load the 24 selected Q rows
    for (int i = tid; i < NTOP * 64; i += 256) {
        int u = i >> 6, d = i & 63;
        int qi = idx_top[bh * NTOP + u];
        Qs[u][d] = qkv[((size_t)(b * SEQ + qi)) * QKVLD + h * HD + d];
    }
    float m[6], s[6], o[6], alpha[6];
#pragma unroll
    for (int j = 0; j < 6; j++) { m[j] = -INFINITY; s[j] = 0.f; o[j] = 0.f; }
    int key0 = slab * 512;
    int sr = tid >> 2, sc0 = (tid & 3) * 16;
    for (int t = 0; t < 8; t++) {
        int kbase = key0 + t * 64;
        __syncthreads();
        // stage K (transposed) and V: 256 threads x 16 floats each per matrix
        const float* kr = qkv + ((size_t)(b * SEQ + kbase + sr)) * QKVLD + 512 + h * HD + sc0;
        const float* vr = qkv + ((size_t)(b * SEQ + kbase + sr)) * QKVLD + 1024 + h * HD + sc0;
        float kf[16], vf[16];
        *(float4*)&kf[0]  = *(const float4*)(kr);
        *(float4*)&kf[4]  = *(const float4*)(kr + 4);
        *(float4*)&kf[8]  = *(const float4*)(kr + 8);
        *(float4*)&kf[12] = *(const float4*)(kr + 12);
        *(float4*)&vf[0]  = *(const float4*)(vr);
        *(float4*)&vf[4]  = *(const float4*)(vr + 4);
        *(float4*)&vf[8]  = *(const float4*)(vr + 8);
        *(float4*)&vf[12] = *(const float4*)(vr + 12);
#pragma unroll
        for (int i = 0; i < 16; i++) {
            KtT[sc0 + i][sr] = kf[i];
            Vt[sr][sc0 + i] = vf[i];
        }
        __syncthreads();
        // phase A: lane = key, wave wv owns queries 6wv..6wv+5
        float dot[6] = {};
#pragma unroll
        for (int d = 0; d < 64; d++) {
            float kv = KtT[d][lane];
#pragma unroll
            for (int j = 0; j < 6; j++) dot[j] += Qs[wv * 6 + j][d] * kv;
        }
#pragma unroll
        for (int j = 0; j < 6; j++) {
            float sc = dot[j] * 0.125f;  // 1/sqrt(64)
            float tmax = sc;
            for (int off = 32; off > 0; off >>= 1) tmax = fmaxf(tmax, __shfl_xor(tmax, off));
            float mn = fmaxf(m[j], tmax);
            float p = __expf(sc - mn);
            float psum = p;
            for (int off = 32; off > 0; off >>= 1) psum += __shfl_xor(psum, off);
            alpha[j] = __expf(m[j] - mn);
            s[j] = s[j] * alpha[j] + psum;
            m[j] = mn;
            Ps[wv * 6 + j][lane] = p;
        }
        // phase B: lane = dim (wave-local, Ps written/read by same wave)
        float pv[6] = {};
#pragma unroll
        for (int key = 0; key < 64; key++) {
            float vvv = Vt[key][lane];
#pragma unroll
            for (int j = 0; j < 6; j++) pv[j] += Ps[wv * 6 + j][key] * vvv;
        }
#pragma unroll
        for (int j = 0; j < 6; j++) o[j] = o[j] * alpha[j] + pv[j];
    }
    // write partials
    float* ob = opart + ((size_t)(bh * 4 + slab)) * NTOP * 64;
#pragma unroll
    for (int j = 0; j < 6; j++) ob[(wv * 6 + j) * 64 + lane] = o[j];
    if (lane == 0) {
        float* ms = mspart + ((size_t)(bh * 4 + slab)) * NTOP * 2;
#pragma unroll
        for (int j = 0; j < 6; j++) {
            ms[(wv * 6 + j) * 2]     = m[j];
            ms[(wv * 6 + j) * 2 + 1] = s[j];
        }
    }
}

// ---------------- merge 4 slab partials, scatter into context ----------------
__global__ __launch_bounds__(256) void spattn_combine(const float* __restrict__ opart,
        const float* __restrict__ mspart, const int* __restrict__ idx_top,
        float* __restrict__ out) {
    __shared__ float wgt[4][NTOP];
    int bh = blockIdx.x;
    int b = bh >> 3, h = bh & 7;
    int tid = threadIdx.x;
    if (tid < NTOP) {
        float mv[4], sv[4];
        float M = -INFINITY;
#pragma unroll
        for (int sl = 0; sl < 4; sl++) {
            mv[sl] = mspart[((size_t)(bh * 4 + sl)) * NTOP * 2 + tid * 2];
            sv[sl] = mspart[((size_t)(bh * 4 + sl)) * NTOP * 2 + tid * 2 + 1];
            M = fmaxf(M, mv[sl]);
        }
        float S = 0.f;
#pragma unroll
        for (int sl = 0; sl < 4; sl++) S += sv[sl] * __expf(mv[sl] - M);
        float invS = 1.f / S;
#pragma unroll
        for (int sl = 0; sl < 4; sl++) wgt[sl][tid] = __expf(mv[sl] - M) * invS;
    }
    __syncthreads();
    for (int i = tid; i < NTOP * 64; i += 256) {
        int u = i >> 6, d = i & 63;
        float val = 0.f;
#pragma unroll
        for (int sl = 0; sl < 4; sl++)
            val += wgt[sl][u] * opart[(((size_t)(bh * 4 + sl)) * NTOP + u) * 64 + d];
        int qi = idx_top[bh * NTOP + u];
        out[((size_t)(b * SEQ + qi)) * DM + h * HD + d] = val;
    }
}

// ---------------- layernorm over DM=512 ----------------
__global__ __launch_bounds__(256) void ln_kernel(const float* src,
        const float* __restrict__ g, const float* __restrict__ b, float* dst) {
    __shared__ float red[256];
    int t = blockIdx.x, tid = threadIdx.x;
    const float* xr = src + (size_t)t * DM;
    float x0 = xr[tid], x1 = xr[tid + 256];
    red[tid] = x0 + x1; __syncthreads();
    for (int s = 128; s > 0; s >>= 1) { if (tid < s) red[tid] += red[tid + s]; __syncthreads(); }
    float m = red[0] * (1.f / DM);
    __syncthreads();
    float d0 = x0 - m, d1 = x1 - m;
    red[tid] = d0 * d0 + d1 * d1; __syncthreads();
    for (int s = 128; s > 0; s >>= 1) { if (tid < s) red[tid] += red[tid + s]; __syncthreads(); }
    float inv = rsqrtf(red[0] * (1.f / DM) + EPS);
    float* dr = dst + (size_t)t * DM;
    dr[tid] = d0 * inv * g[tid] + b[tid];
    dr[tid + 256] = d1 * inv * g[tid + 256] + b[tid + 256];
}

// ---------------- prediction head on last token ----------------
__global__ __launch_bounds__(256) void head_kernel(const float* __restrict__ hfin,
        const float* __restrict__ Wpre, const float* __restrict__ bpre,
        const float* __restrict__ Wfc, const float* __restrict__ bfc,
        float* __restrict__ out) {
    __shared__ float last[DM];
    __shared__ float red[256];
    int b = blockIdx.x, tid = threadIdx.x;
    const float* hr = hfin + ((size_t)(b * SEQ + SEQ - 1)) * DM;
    last[tid] = hr[tid];
    last[tid + 256] = hr[tid + 256];
    __syncthreads();
    float acc = bpre[tid];
    for (int c = 0; c < DM; c++) acc += last[c] * Wpre[tid * DM + c];
    acc = fmaxf(acc, 0.f);
    red[tid] = acc * Wfc[tid];
    __syncthreads();
    for (int s = 128; s > 0; s >>= 1) { if (tid < s) red[tid] += red[tid + s]; __syncthreads(); }
    if (tid == 0) out[b] = red[0] + bfc[0];
}

extern "C" void kernel_launch(void* const* d_in, const int* in_sizes, int n_in,
                              void* d_out, int out_size, void* d_ws, size_t ws_size,
                              hipStream_t stream) {
    (void)in_sizes; (void)n_in; (void)out_size; (void)ws_size;
    const float* x      = (const float*)d_in[0];
    const float* tfeat  = (const float*)d_in[1];
    const float* g_in   = (const float*)d_in[2];
    const float* b_in   = (const float*)d_in[3];
    const float* W_tok  = (const float*)d_in[4];
    const float* W_time = (const float*)d_in[5];
    const float* b_time = (const float*)d_in[6];
    const float* Wq     = (const float*)d_in[7];
    const float* bq     = (const float*)d_in[8];
    const float* Wk     = (const float*)d_in[9];
    const float* bk     = (const float*)d_in[10];
    const float* Wv     = (const float*)d_in[11];
    const float* bv     = (const float*)d_in[12];
    const float* Wo     = (const float*)d_in[13];
    const float* bo     = (const float*)d_in[14];
    const float* W1     = (const float*)d_in[15];
    const float* b1     = (const float*)d_in[16];
    const float* W2     = (const float*)d_in[17];
    const float* b2     = (const float*)d_in[18];
    const float* g1     = (const float*)d_in[19];
    const float* be1    = (const float*)d_in[20];
    const float* g2     = (const float*)d_in[21];
    const float* be2    = (const float*)d_in[22];
    const float* g_enc  = (const float*)d_in[23];
    const float* b_enc  = (const float*)d_in[24];
    const float* W_pre  = (const float*)d_in[25];
    const float* b_pre  = (const float*)d_in[26];
    const float* W_fc   = (const float*)d_in[27];
    const float* b_fc   = (const float*)d_in[28];
    float* out = (float*)d_out;

    char* ws = (char*)d_ws;
    float* h    = (float*)(ws);                      // 33.5 MB
    float* tmp  = (float*)(ws + 33554432);           // 33.5 MB
    float* big  = (float*)(ws + 67108864);           // 134.2 MB: qkv packed OR ffn mid
    u16*   wh   = (u16*)(ws + 201326592);            // 6.3 MB
    u16*   wl   = (u16*)(ws + 207618048);            // 6.3 MB
    float* xln  = (float*)(ws + 213909504);          // 2 MB (overlaid by opart/mspart later)
    float* opart  = (float*)(ws + 213909504);        // 1.57 MB (after embed)
    float* mspart = (float*)(ws + 215482368);        // 48 KB
    float* Mbuf       = (float*)(ws + 216006656);
    float* vmean      = (float*)(ws + 216530944);
    int*   idx_sample = (int*)(ws + 216547328);
    int*   idx_top    = (int*)(ws + 216940544);
    float* biasqkv    = (float*)(ws + 216946688);

    ln_in_kernel<<<TOK / 256, 256, 0, stream>>>(x, g_in, b_in, xln);
    embed_kernel<<<TOK, 256, 0, stream>>>(xln, tfeat, W_tok, W_time, b_time, h);
    sample_kernel<<<dim3(96, 2), 256, 0, stream>>>(idx_sample);

    const u16* wqkv_h = wh;                 // rows 0..1535 = Wq;Wk;Wv
    const u16* wqkv_l = wl;
    const u16* wo_h = wh + 786432,  *wo_l = wl + 786432;
    const u16* w1_h = wh + 1048576, *w1_l = wl + 1048576;
    const u16* w2_h = wh + 2097152, *w2_l = wl + 2097152;

    for (int li = 0; li < 2; li++) {
        split_weights<<<12288, 256, 0, stream>>>(
            Wq + (size_t)li * DM * DM, Wk + (size_t)li * DM * DM,
            Wv + (size_t)li * DM * DM, Wo + (size_t)li * DM * DM,
            W1 + (size_t)li * DFF * DM, W2 + (size_t)li * DM * DFF, wh, wl);
        concat_bias<<<6, 256, 0, stream>>>(bq + (size_t)li * DM, bk + (size_t)li * DM,
                                           bv + (size_t)li * DM, biasqkv);

        const float* bo_i = bo + (size_t)li * DM;
        const float* b1_i = b1 + (size_t)li * DFF;
        const float* b2_i = b2 + (size_t)li * DM;
        const float* g1_i = g1 + (size_t)li * DM;
        const float* be1_i = be1 + (size_t)li * DM;
        const float* g2_i = g2 + (size_t)li * DM;
        const float* be2_i = be2 + (size_t)li * DM;

        // fused QKV: [TOK][1536]
        gemm_split<false, false><<<dim3(QKVLD / 128, TOK / 128), 256, 0, stream>>>(
            h, wqkv_h, wqkv_l, biasqkv, nullptr, big, QKVLD, DM, DM);

        qk_sample_kernel<<<(BATCH * NH * SEQ) / 4, 256, 0, stream>>>(
            big, idx_sample + li * SEQ * NSAMP, Mbuf);
        topk_kernel<<<BATCH * NH, 256, 0, stream>>>(Mbuf, idx_top);
        hipMemsetAsync(vmean, 0, BATCH * NH * HD * sizeof(float), stream);
        vmean_kernel<<<dim3(BATCH * NH, 8), 256, 0, stream>>>(big, vmean);
        fillctx_kernel<<<(TOK * DM) / 256, 256, 0, stream>>>(vmean, tmp);
        spattn_flash<<<dim3(BATCH * NH, 4), 256, 0, stream>>>(big, idx_top, opart, mspart);
        spattn_combine<<<BATCH * NH, 256, 0, stream>>>(opart, mspart, idx_top, tmp);

        gemm_split<false, true><<<dim3(DM / 128, TOK / 128), 256, 0, stream>>>(
            tmp, wo_h, wo_l, bo_i, h, h, DM, DM, DM);
        ln_kernel<<<TOK, 256, 0, stream>>>(h, g1_i, be1_i, h);

        gemm_split<true, false><<<dim3(DFF / 128, TOK / 128), 256, 0, stream>>>(
            h, w1_h, w1_l, b1_i, nullptr, big, DFF, DM, DM);
        gemm_split<false, true><<<dim3(DM / 128, TOK / 128), 256, 0, stream>>>(
            big, w2_h, w2_l, b2_i, h, tmp, DM, DFF, DFF);
        ln_kernel<<<TOK, 256, 0, stream>>>(tmp, g2_i, be2_i, h);
    }

    ln_kernel<<<TOK, 256, 0, stream>>>(h, g_enc, b_enc, tmp);
    head_kernel<<<BATCH, 256, 0, stream>>>(tmp, W_pre, b_pre, W_fc, b_fc, out);
}

// Round 4
// 1517.924 us; speedup vs baseline: 3.0258x; 1.1951x over previous
//
#include <hip/hip_runtime.h>
#include <math.h>

#define BATCH 8
#define SEQ   2048
#define TOK   (BATCH*SEQ)     // 16384
#define CIN   32
#define DM    512
#define DFF   2048
#define NH    8
#define HD    64
#define NSAMP 24
#define NTOP  24
#define EPS   1e-5f
#define QKVLD 1536

typedef unsigned int u32;
typedef unsigned short u16;
typedef unsigned long long u64;
typedef __attribute__((ext_vector_type(8))) short short8;
typedef __attribute__((ext_vector_type(4))) float floatx4;

__device__ __forceinline__ void async16(const void* g, void* l) {
    __builtin_amdgcn_global_load_lds((const __attribute__((address_space(1))) u32*)g,
                                     (__attribute__((address_space(3))) u32*)l, 16, 0, 0);
}
__device__ __forceinline__ u16 bf16rn(float f) {
    u32 u = __float_as_uint(f);
    return (u16)((u + 0x7fffu + ((u >> 16) & 1u)) >> 16);
}

// ---------------- Threefry-2x32 ----------------
__device__ __forceinline__ void tf_round(unsigned &x0, unsigned &x1, int r) {
    x0 += x1;
    x1 = (x1 << r) | (x1 >> (32 - r));
    x1 ^= x0;
}
__device__ __forceinline__ void threefry(unsigned k0, unsigned k1,
                                         unsigned c0, unsigned c1,
                                         unsigned &o0, unsigned &o1) {
    unsigned ks0 = k0, ks1 = k1, ks2 = k0 ^ k1 ^ 0x1BD11BDAu;
    unsigned x0 = c0 + ks0, x1 = c1 + ks1;
    tf_round(x0,x1,13); tf_round(x0,x1,15); tf_round(x0,x1,26); tf_round(x0,x1,6);
    x0 += ks1; x1 += ks2 + 1u;
    tf_round(x0,x1,17); tf_round(x0,x1,29); tf_round(x0,x1,16); tf_round(x0,x1,24);
    x0 += ks2; x1 += ks0 + 2u;
    tf_round(x0,x1,13); tf_round(x0,x1,15); tf_round(x0,x1,26); tf_round(x0,x1,6);
    x0 += ks0; x1 += ks1 + 3u;
    tf_round(x0,x1,17); tf_round(x0,x1,29); tf_round(x0,x1,16); tf_round(x0,x1,24);
    x0 += ks1; x1 += ks2 + 4u;
    tf_round(x0,x1,13); tf_round(x0,x1,15); tf_round(x0,x1,26); tf_round(x0,x1,6);
    x0 += ks2; x1 += ks0 + 5u;
    o0 = x0; o1 = x1;
}

__global__ void sample_kernel(int* __restrict__ idx_sample) {
    const int HALF = (SEQ * NSAMP) / 2;  // 24576
    int p = blockIdx.x * blockDim.x + threadIdx.x;
    int li = blockIdx.y;
    if (p >= HALF) return;
    unsigned f0, f1;
    threefry(0u, 42u, 0u, (unsigned)li, f0, f1);
    unsigned a0, a1, b0, b1;
    threefry(f0, f1, 0u, 2u, a0, a1);
    threefry(f0, f1, 1u, 3u, b0, b1);
    unsigned o0, o1;
    threefry(a1, b1, (unsigned)p, (unsigned)(p + HALF), o0, o1);
    idx_sample[li * SEQ * NSAMP + p]        = (int)(o0 & (SEQ - 1));
    idx_sample[li * SEQ * NSAMP + p + HALF] = (int)(o1 & (SEQ - 1));
}

// ---------------- input layernorm over C_IN=32 ----------------
__global__ __launch_bounds__(256) void ln_in_kernel(const float* __restrict__ x,
        const float* __restrict__ g, const float* __restrict__ b,
        float* __restrict__ out) {
    int t = blockIdx.x * blockDim.x + threadIdx.x;
    if (t >= TOK) return;
    const float* xr = x + (size_t)t * CIN;
    float vals[CIN];
    float s = 0.f;
#pragma unroll
    for (int c = 0; c < CIN; c++) { vals[c] = xr[c]; s += vals[c]; }
    float m = s * (1.f / CIN);
    float v = 0.f;
#pragma unroll
    for (int c = 0; c < CIN; c++) { float d = vals[c] - m; v += d * d; }
    v *= (1.f / CIN);
    float inv = rsqrtf(v + EPS);
    float* orow = out + (size_t)t * CIN;
#pragma unroll
    for (int c = 0; c < CIN; c++) orow[c] = (vals[c] - m) * inv * g[c] + b[c];
}

// ---------------- token conv + pos emb + time emb ----------------
__global__ __launch_bounds__(256) void embed_kernel(const float* __restrict__ xln,
        const float* __restrict__ tfeat, const float* __restrict__ Wtok,
        const float* __restrict__ Wtime, const float* __restrict__ btime,
        float* __restrict__ h) {
    __shared__ float xs[96];
    __shared__ float tf4[4];
    int t = blockIdx.x;
    int b = t / SEQ, l = t % SEQ;
    int tid = threadIdx.x;
    if (tid < 96) {
        int w = tid / 32, c = tid % 32;
        int lw = (l - 1 + w + SEQ) % SEQ;
        xs[tid] = xln[((size_t)b * SEQ + lw) * CIN + c];
    }
    if (tid < 4) tf4[tid] = tfeat[((size_t)b * SEQ + l) * 4 + tid];
    __syncthreads();
    const float c1 = -0.017988946039016f;  // -ln(10000)/512
    for (int o = tid; o < DM; o += 256) {
        float acc = btime[o];
        for (int j = 0; j < 96; j++) acc += xs[j] * Wtok[j * DM + o];
        acc += tf4[0] * Wtime[o * 4 + 0] + tf4[1] * Wtime[o * 4 + 1]
             + tf4[2] * Wtime[o * 4 + 2] + tf4[3] * Wtime[o * 4 + 3];
        int i2 = o & ~1;
        float div = expf((float)i2 * c1);
        float arg = (float)l * div;
        float pe = (o & 1) ? cosf(arg) : sinf(arg);
        h[(size_t)t * DM + o] = acc + pe;
    }
}

// ---------------- weight split: fp32 -> separate bf16 high/low buffers ----------------
__global__ __launch_bounds__(256) void split_weights(const float* __restrict__ Wq,
        const float* __restrict__ Wk, const float* __restrict__ Wv,
        const float* __restrict__ Wo, const float* __restrict__ W1,
        const float* __restrict__ W2, u16* __restrict__ wh, u16* __restrict__ wl) {
    int i = blockIdx.x * 256 + threadIdx.x;  // < 3145728
    const float* src; int off;
    if (i < 1048576) {
        src = (i < 262144) ? Wq : (i < 524288) ? Wk : (i < 786432) ? Wv : Wo;
        off = i & 262143;
    } else if (i < 2097152) { src = W1; off = i - 1048576; }
    else { src = W2; off = i - 2097152; }
    float f = src[off];
    u16 h = bf16rn(f);
    u16 l = bf16rn(f - __uint_as_float((u32)h << 16));
    wh[i] = h;
    wl[i] = l;
}

__global__ void concat_bias(const float* __restrict__ bq, const float* __restrict__ bk,
                            const float* __restrict__ bv, float* __restrict__ o) {
    int i = blockIdx.x * 256 + threadIdx.x;  // < 1536
    o[i] = (i < 512) ? bq[i] : (i < 1024) ? bk[i - 512] : bv[i - 1024];
}

// ---------------- split-bf16 MFMA GEMM: C = A[MxK]*W[NxK]^T + bias (+res)(+relu) ----------
template<bool RELU, bool RES>
__global__ __launch_bounds__(256, 2) void gemm_split(const float* __restrict__ A,
        const u16* __restrict__ Wh, const u16* __restrict__ Wl,
        const float* __restrict__ bias, const float* __restrict__ Rsd,
        float* __restrict__ C, int ldc, int K, int lda) {
    __shared__ alignas(16) u16 AhS[128 * 40];     // padded stride 40
    __shared__ alignas(16) u16 AlS[128 * 40];
    __shared__ alignas(16) u16 WhS[4 * 128 * 8];  // [kchunk][row][8] bf16
    __shared__ alignas(16) u16 WlS[4 * 128 * 8];
    const int tid = threadIdx.x;
    const int m0 = blockIdx.y * 128, n0 = blockIdx.x * 128;
    const int lane = tid & 63, wv = tid >> 6;
    const int wm = wv >> 1, wn = wv & 1;
    const int fr = lane & 15, q = lane >> 4;

    floatx4 acc[4][4] = {};

    const int arow = tid >> 1, ahalf = tid & 1;
    const float* abase = A + (size_t)(m0 + arow) * lda + ahalf * 16;
    const int wrow = tid & 127, wc0 = tid >> 7;
    const u16* whbase = Wh + (size_t)(n0 + wrow) * K + wc0 * 8;
    const u16* wlbase = Wl + (size_t)(n0 + wrow) * K + wc0 * 8;
    char* whdst = (char*)WhS + tid * 16;
    char* wldst = (char*)WlS + tid * 16;
    u16* ahw = &AhS[arow * 40 + ahalf * 16];
    u16* alw = &AlS[arow * 40 + ahalf * 16];

    for (int k0 = 0; k0 < K; k0 += 32) {
        // --- stage W tiles (async DMA, fragment-layout chunks) ---
#pragma unroll
        for (int i = 0; i < 2; i++) {
            async16(whbase + k0 + i * 16, whdst + i * 4096);
            async16(wlbase + k0 + i * 16, wldst + i * 4096);
        }
        // --- stage A tile: fp32 load, split to bf16 h/l ---
        const float* ap = abase + k0;
        float f[16];
        *(float4*)&f[0]  = *(const float4*)(ap);
        *(float4*)&f[4]  = *(const float4*)(ap + 4);
        *(float4*)&f[8]  = *(const float4*)(ap + 8);
        *(float4*)&f[12] = *(const float4*)(ap + 12);
        short8 h0, h1, l0, l1;
#pragma unroll
        for (int j = 0; j < 8; j++) {
            u16 hb = bf16rn(f[j]);
            float r = f[j] - __uint_as_float((u32)hb << 16);
            h0[j] = (short)hb; l0[j] = (short)bf16rn(r);
            u16 hb2 = bf16rn(f[j + 8]);
            float r2 = f[j + 8] - __uint_as_float((u32)hb2 << 16);
            h1[j] = (short)hb2; l1[j] = (short)bf16rn(r2);
        }
        *(short8*)(ahw)     = h0;  *(short8*)(ahw + 8) = h1;
        *(short8*)(alw)     = l0;  *(short8*)(alw + 8) = l1;
        __syncthreads();
        // --- fragments + MFMA ---
        short8 ah[4], al[4];
#pragma unroll
        for (int mi = 0; mi < 4; mi++) {
            int off = (wm * 64 + mi * 16 + fr) * 40 + q * 8;
            ah[mi] = *(const short8*)&AhS[off];
            al[mi] = *(const short8*)&AlS[off];
        }
#pragma unroll
        for (int ni = 0; ni < 4; ni++) {
            int woff = (q * 128 + wn * 64 + ni * 16 + fr) * 8;
            short8 wh8 = *(const short8*)&WhS[woff];
            short8 wl8 = *(const short8*)&WlS[woff];
#pragma unroll
            for (int mi = 0; mi < 4; mi++) {
                acc[mi][ni] = __builtin_amdgcn_mfma_f32_16x16x32_bf16(ah[mi], wh8, acc[mi][ni], 0, 0, 0);
                acc[mi][ni] = __builtin_amdgcn_mfma_f32_16x16x32_bf16(ah[mi], wl8, acc[mi][ni], 0, 0, 0);
                acc[mi][ni] = __builtin_amdgcn_mfma_f32_16x16x32_bf16(al[mi], wh8, acc[mi][ni], 0, 0, 0);
            }
        }
        __syncthreads();
    }
    // --- epilogue ---
#pragma unroll
    for (int ni = 0; ni < 4; ni++) {
        int col = n0 + wn * 64 + ni * 16 + fr;
        float bv = bias[col];
#pragma unroll
        for (int mi = 0; mi < 4; mi++) {
            int row = m0 + wm * 64 + mi * 16 + q * 4;
#pragma unroll
            for (int r = 0; r < 4; r++) {
                size_t idx = (size_t)(row + r) * ldc + col;
                float v = acc[mi][ni][r] + bv;
                if (RES) v += Rsd[idx];
                if (RELU) v = fmaxf(v, 0.f);
                C[idx] = v;
            }
        }
    }
}

// ---------------- M = max(QK_sample) - sum/L : one wave per (b,h,l) ----------------
// lane = (sample-group sidx 0..3, d-chunk dc 0..15); 6 passes of 4 samples.
__global__ __launch_bounds__(256) void qk_sample_kernel(const float* __restrict__ qkv,
        const int* __restrict__ idx_sample, float* __restrict__ Mout) {
    int r = (blockIdx.x * 256 + threadIdx.x) >> 6;
    int lane = threadIdx.x & 63;
    if (r >= BATCH * NH * SEQ) return;
    int b = r / (NH * SEQ);
    int head = (r / SEQ) % NH;
    int l = r % SEQ;
    int sidx = lane >> 4, dc = lane & 15;
    const float* qrow = qkv + ((size_t)(b * SEQ + l)) * QKVLD + head * HD + dc * 4;
    float4 qf = *(const float4*)qrow;
    int myidx = (lane < NSAMP) ? idx_sample[l * NSAMP + lane] : 0;
    const float* kbase = qkv + (size_t)b * SEQ * QKVLD + 512 + head * HD + dc * 4;
    float mx = -INFINITY, sm = 0.f;
#pragma unroll
    for (int p = 0; p < 6; p++) {
        int s = p * 4 + sidx;
        int kidx = __shfl(myidx, s);
        float4 kf = *(const float4*)(kbase + (size_t)kidx * QKVLD);
        float part = qf.x * kf.x + qf.y * kf.y + qf.z * kf.z + qf.w * kf.w;
        part += __shfl_xor(part, 1);
        part += __shfl_xor(part, 2);
        part += __shfl_xor(part, 4);
        part += __shfl_xor(part, 8);
        mx = fmaxf(mx, part);
        sm += part;
    }
    mx = fmaxf(mx, __shfl_xor(mx, 16));
    mx = fmaxf(mx, __shfl_xor(mx, 32));
    sm += __shfl_xor(sm, 16);
    sm += __shfl_xor(sm, 32);
    if (lane == 0) Mout[r] = mx - sm * (1.f / SEQ);
}

// ---------------- top-24 two-stage: packed u64 keys, exact (idx unique) ----------------
__device__ __forceinline__ u64 pack_key(float v, int idx) {
    u32 u = __float_as_uint(v);
    u32 m = (u & 0x80000000u) ? ~u : (u | 0x80000000u);
    return ((u64)m << 32) | (u32)(~(u32)idx);
}

__global__ __launch_bounds__(256) void topk_part(const float* __restrict__ Mbuf,
        u64* __restrict__ cand) {
    __shared__ u64 vals[256];
    __shared__ u64 red[256];
    int bh = blockIdx.x, chunk = blockIdx.y;
    int tid = threadIdx.x;
    int l = chunk * 256 + tid;
    vals[tid] = pack_key(Mbuf[(size_t)bh * SEQ + l], l);
    __syncthreads();
    for (int it = 0; it < NTOP; it++) {
        red[tid] = vals[tid];
        __syncthreads();
        for (int s = 128; s > 0; s >>= 1) {
            if (tid < s) { u64 o = red[tid + s]; if (o > red[tid]) red[tid] = o; }
            __syncthreads();
        }
        u64 win = red[0];
        if (vals[tid] == win) vals[tid] = 0;
        if (tid == 0) cand[((size_t)bh * 8 + chunk) * NTOP + it] = win;
        __syncthreads();
    }
}

__global__ __launch_bounds__(256) void topk_merge(const u64* __restrict__ cand,
        int* __restrict__ idx_top) {
    __shared__ u64 vals[256];
    __shared__ u64 red[256];
    int bh = blockIdx.x;
    int tid = threadIdx.x;
    vals[tid] = (tid < 8 * NTOP) ? cand[(size_t)bh * 8 * NTOP + tid] : 0;
    __syncthreads();
    for (int it = 0; it < NTOP; it++) {
        red[tid] = vals[tid];
        __syncthreads();
        for (int s = 128; s > 0; s >>= 1) {
            if (tid < s) { u64 o = red[tid + s]; if (o > red[tid]) red[tid] = o; }
            __syncthreads();
        }
        u64 win = red[0];
        if (vals[tid] == win) vals[tid] = 0;
        if (tid == 0) idx_top[bh * NTOP + it] = (int)(~(u32)(win & 0xffffffffull) & (SEQ - 1));
        __syncthreads();
    }
}

// ---------------- V mean over keys per (b,h) ----------------
__global__ __launch_bounds__(256) void vmean_kernel(const float* __restrict__ qkv,
        float* __restrict__ vmean) {
    __shared__ float red[256];
    int bh = blockIdx.x, slab = blockIdx.y;
    int b = bh >> 3, head = bh & 7;
    int seg = threadIdx.x >> 6, d = threadIdx.x & 63;
    int base_row = slab * 256 + seg * 64;
    float s = 0.f;
    for (int r = 0; r < 64; r++)
        s += qkv[((size_t)(b * SEQ + base_row + r)) * QKVLD + 1024 + head * HD + d];
    red[threadIdx.x] = s;
    __syncthreads();
    if (threadIdx.x < 128) red[threadIdx.x] += red[threadIdx.x + 128];
    __syncthreads();
    if (threadIdx.x < 64) {
        float t = red[threadIdx.x] + red[threadIdx.x + 64];
        atomicAdd(&vmean[bh * HD + d], t * (1.f / SEQ));
    }
}

// ---------------- fill context with V-mean ----------------
__global__ void fillctx_kernel(const float* __restrict__ vmean, float* __restrict__ out) {
    int e = blockIdx.x * 256 + threadIdx.x;
    int c = e % DM;
    int b = e / (SEQ * DM);
    out[e] = vmean[(b * NH + (c / HD)) * HD + (c % HD)];
}

// ---------------- flash-style sparse attention: block = (b*h, key-slab of 512) ----------------
__global__ __launch_bounds__(256) void spattn_flash(const float* __restrict__ qkv,
        const int* __restrict__ idx_top, float* __restrict__ opart,
        float* __restrict__ mspart) {
    __shared__ float KtT[64][65];   // transposed: [dim][key]
    __shared__ float Vt[64][65];    // [key][dim]
    __shared__ float Qs[24][64];
    __shared__ float Ps[24][66];
    int bh = blockIdx.x, slab = blockIdx.y;
    int b = bh >> 3, h = bh & 7;
    int tid = threadIdx.x;
    int wv = tid >> 6, lane = tid & 63;
    for (int i = tid; i < NTOP * 64; i += 256) {
        int u = i >> 6, d = i & 63;
        int qi = idx_top[bh * NTOP + u];
        Qs[u][d] = qkv[((size_t)(b * SEQ + qi)) * QKVLD + h * HD + d];
    }
    float m[6], s[6], o[6], alpha[6];
#pragma unroll
    for (int j = 0; j < 6; j++) { m[j] = -INFINITY; s[j] = 0.f; o[j] = 0.f; }
    int key0 = slab * 512;
    int sr = tid >> 2, sc0 = (tid & 3) * 16;
    for (int t = 0; t < 8; t++) {
        int kbase = key0 + t * 64;
        __syncthreads();
        const float* kr = qkv + ((size_t)(b * SEQ + kbase + sr)) * QKVLD + 512 + h * HD + sc0;
        const float* vr = qkv + ((size_t)(b * SEQ + kbase + sr)) * QKVLD + 1024 + h * HD + sc0;
        float kf[16], vf[16];
        *(float4*)&kf[0]  = *(const float4*)(kr);
        *(float4*)&kf[4]  = *(const float4*)(kr + 4);
        *(float4*)&kf[8]  = *(const float4*)(kr + 8);
        *(float4*)&kf[12] = *(const float4*)(kr + 12);
        *(float4*)&vf[0]  = *(const float4*)(vr);
        *(float4*)&vf[4]  = *(const float4*)(vr + 4);
        *(float4*)&vf[8]  = *(const float4*)(vr + 8);
        *(float4*)&vf[12] = *(const float4*)(vr + 12);
#pragma unroll
        for (int i = 0; i < 16; i++) {
            KtT[sc0 + i][sr] = kf[i];
            Vt[sr][sc0 + i] = vf[i];
        }
        __syncthreads();
        float dot[6] = {};
#pragma unroll
        for (int d = 0; d < 64; d++) {
            float kv = KtT[d][lane];
#pragma unroll
            for (int j = 0; j < 6; j++) dot[j] += Qs[wv * 6 + j][d] * kv;
        }
#pragma unroll
        for (int j = 0; j < 6; j++) {
            float sc = dot[j] * 0.125f;
            float tmax = sc;
            for (int off = 32; off > 0; off >>= 1) tmax = fmaxf(tmax, __shfl_xor(tmax, off));
            float mn = fmaxf(m[j], tmax);
            float p = __expf(sc - mn);
            float psum = p;
            for (int off = 32; off > 0; off >>= 1) psum += __shfl_xor(psum, off);
            alpha[j] = __expf(m[j] - mn);
            s[j] = s[j] * alpha[j] + psum;
            m[j] = mn;
            Ps[wv * 6 + j][lane] = p;
        }
        float pv[6] = {};
#pragma unroll
        for (int key = 0; key < 64; key++) {
            float vvv = Vt[key][lane];
#pragma unroll
            for (int j = 0; j < 6; j++) pv[j] += Ps[wv * 6 + j][key] * vvv;
        }
#pragma unroll
        for (int j = 0; j < 6; j++) o[j] = o[j] * alpha[j] + pv[j];
    }
    float* ob = opart + ((size_t)(bh * 4 + slab)) * NTOP * 64;
#pragma unroll
    for (int j = 0; j < 6; j++) ob[(wv * 6 + j) * 64 + lane] = o[j];
    if (lane == 0) {
        float* ms = mspart + ((size_t)(bh * 4 + slab)) * NTOP * 2;
#pragma unroll
        for (int j = 0; j < 6; j++) {
            ms[(wv * 6 + j) * 2]     = m[j];
            ms[(wv * 6 + j) * 2 + 1] = s[j];
        }
    }
}

// ---------------- merge 4 slab partials, scatter into context ----------------
__global__ __launch_bounds__(256) void spattn_combine(const float* __restrict__ opart,
        const float* __restrict__ mspart, const int* __restrict__ idx_top,
        float* __restrict__ out) {
    __shared__ float wgt[4][NTOP];
    int bh = blockIdx.x;
    int b = bh >> 3, h = bh & 7;
    int tid = threadIdx.x;
    if (tid < NTOP) {
        float mv[4], sv[4];
        float M = -INFINITY;
#pragma unroll
        for (int sl = 0; sl < 4; sl++) {
            mv[sl] = mspart[((size_t)(bh * 4 + sl)) * NTOP * 2 + tid * 2];
            sv[sl] = mspart[((size_t)(bh * 4 + sl)) * NTOP * 2 + tid * 2 + 1];
            M = fmaxf(M, mv[sl]);
        }
        float S = 0.f;
#pragma unroll
        for (int sl = 0; sl < 4; sl++) S += sv[sl] * __expf(mv[sl] - M);
        float invS = 1.f / S;
#pragma unroll
        for (int sl = 0; sl < 4; sl++) wgt[sl][tid] = __expf(mv[sl] - M) * invS;
    }
    __syncthreads();
    for (int i = tid; i < NTOP * 64; i += 256) {
        int u = i >> 6, d = i & 63;
        float val = 0.f;
#pragma unroll
        for (int sl = 0; sl < 4; sl++)
            val += wgt[sl][u] * opart[(((size_t)(bh * 4 + sl)) * NTOP + u) * 64 + d];
        int qi = idx_top[bh * NTOP + u];
        out[((size_t)(b * SEQ + qi)) * DM + h * HD + d] = val;
    }
}

// ---------------- layernorm over DM=512 ----------------
__global__ __launch_bounds__(256) void ln_kernel(const float* src,
        const float* __restrict__ g, const float* __restrict__ b, float* dst) {
    __shared__ float red[256];
    int t = blockIdx.x, tid = threadIdx.x;
    const float* xr = src + (size_t)t * DM;
    float x0 = xr[tid], x1 = xr[tid + 256];
    red[tid] = x0 + x1; __syncthreads();
    for (int s = 128; s > 0; s >>= 1) { if (tid < s) red[tid] += red[tid + s]; __syncthreads(); }
    float m = red[0] * (1.f / DM);
    __syncthreads();
    float d0 = x0 - m, d1 = x1 - m;
    red[tid] = d0 * d0 + d1 * d1; __syncthreads();
    for (int s = 128; s > 0; s >>= 1) { if (tid < s) red[tid] += red[tid + s]; __syncthreads(); }
    float inv = rsqrtf(red[0] * (1.f / DM) + EPS);
    float* dr = dst + (size_t)t * DM;
    dr[tid] = d0 * inv * g[tid] + b[tid];
    dr[tid + 256] = d1 * inv * g[tid + 256] + b[tid + 256];
}

// ---------------- prediction head on last token ----------------
__global__ __launch_bounds__(256) void head_kernel(const float* __restrict__ hfin,
        const float* __restrict__ Wpre, const float* __restrict__ bpre,
        const float* __restrict__ Wfc, const float* __restrict__ bfc,
        float* __restrict__ out) {
    __shared__ float last[DM];
    __shared__ float red[256];
    int b = blockIdx.x, tid = threadIdx.x;
    const float* hr = hfin + ((size_t)(b * SEQ + SEQ - 1)) * DM;
    last[tid] = hr[tid];
    last[tid + 256] = hr[tid + 256];
    __syncthreads();
    float acc = bpre[tid];
    for (int c = 0; c < DM; c++) acc += last[c] * Wpre[tid * DM + c];
    acc = fmaxf(acc, 0.f);
    red[tid] = acc * Wfc[tid];
    __syncthreads();
    for (int s = 128; s > 0; s >>= 1) { if (tid < s) red[tid] += red[tid + s]; __syncthreads(); }
    if (tid == 0) out[b] = red[0] + bfc[0];
}

extern "C" void kernel_launch(void* const* d_in, const int* in_sizes, int n_in,
                              void* d_out, int out_size, void* d_ws, size_t ws_size,
                              hipStream_t stream) {
    (void)in_sizes; (void)n_in; (void)out_size; (void)ws_size;
    const float* x      = (const float*)d_in[0];
    const float* tfeat  = (const float*)d_in[1];
    const float* g_in   = (const float*)d_in[2];
    const float* b_in   = (const float*)d_in[3];
    const float* W_tok  = (const float*)d_in[4];
    const float* W_time = (const float*)d_in[5];
    const float* b_time = (const float*)d_in[6];
    const float* Wq     = (const float*)d_in[7];
    const float* bq     = (const float*)d_in[8];
    const float* Wk     = (const float*)d_in[9];
    const float* bk     = (const float*)d_in[10];
    const float* Wv     = (const float*)d_in[11];
    const float* bv     = (const float*)d_in[12];
    const float* Wo     = (const float*)d_in[13];
    const float* bo     = (const float*)d_in[14];
    const float* W1     = (const float*)d_in[15];
    const float* b1     = (const float*)d_in[16];
    const float* W2     = (const float*)d_in[17];
    const float* b2     = (const float*)d_in[18];
    const float* g1     = (const float*)d_in[19];
    const float* be1    = (const float*)d_in[20];
    const float* g2     = (const float*)d_in[21];
    const float* be2    = (const float*)d_in[22];
    const float* g_enc  = (const float*)d_in[23];
    const float* b_enc  = (const float*)d_in[24];
    const float* W_pre  = (const float*)d_in[25];
    const float* b_pre  = (const float*)d_in[26];
    const float* W_fc   = (const float*)d_in[27];
    const float* b_fc   = (const float*)d_in[28];
    float* out = (float*)d_out;

    char* ws = (char*)d_ws;
    float* h    = (float*)(ws);                      // 33.5 MB
    float* tmp  = (float*)(ws + 33554432);           // 33.5 MB
    float* big  = (float*)(ws + 67108864);           // 134.2 MB: qkv packed OR ffn mid
    u16*   wh   = (u16*)(ws + 201326592);            // 6.3 MB
    u16*   wl   = (u16*)(ws + 207618048);            // 6.3 MB
    float* xln  = (float*)(ws + 213909504);          // 2 MB (overlaid by opart/mspart later)
    float* opart  = (float*)(ws + 213909504);        // 1.57 MB (after embed)
    float* mspart = (float*)(ws + 215482368);        // 48 KB
    float* Mbuf       = (float*)(ws + 216006656);
    float* vmean      = (float*)(ws + 216530944);
    int*   idx_sample = (int*)(ws + 216547328);
    int*   idx_top    = (int*)(ws + 216940544);
    float* biasqkv    = (float*)(ws + 216946688);
    u64*   cand       = (u64*)(ws + 216952832);      // 98 KB

    ln_in_kernel<<<TOK / 256, 256, 0, stream>>>(x, g_in, b_in, xln);
    embed_kernel<<<TOK, 256, 0, stream>>>(xln, tfeat, W_tok, W_time, b_time, h);
    sample_kernel<<<dim3(96, 2), 256, 0, stream>>>(idx_sample);

    const u16* wqkv_h = wh;                 // rows 0..1535 = Wq;Wk;Wv
    const u16* wqkv_l = wl;
    const u16* wo_h = wh + 786432,  *wo_l = wl + 786432;
    const u16* w1_h = wh + 1048576, *w1_l = wl + 1048576;
    const u16* w2_h = wh + 2097152, *w2_l = wl + 2097152;

    for (int li = 0; li < 2; li++) {
        split_weights<<<12288, 256, 0, stream>>>(
            Wq + (size_t)li * DM * DM, Wk + (size_t)li * DM * DM,
            Wv + (size_t)li * DM * DM, Wo + (size_t)li * DM * DM,
            W1 + (size_t)li * DFF * DM, W2 + (size_t)li * DM * DFF, wh, wl);
        concat_bias<<<6, 256, 0, stream>>>(bq + (size_t)li * DM, bk + (size_t)li * DM,
                                           bv + (size_t)li * DM, biasqkv);

        const float* bo_i = bo + (size_t)li * DM;
        const float* b1_i = b1 + (size_t)li * DFF;
        const float* b2_i = b2 + (size_t)li * DM;
        const float* g1_i = g1 + (size_t)li * DM;
        const float* be1_i = be1 + (size_t)li * DM;
        const float* g2_i = g2 + (size_t)li * DM;
        const float* be2_i = be2 + (size_t)li * DM;

        // fused QKV: [TOK][1536]
        gemm_split<false, false><<<dim3(QKVLD / 128, TOK / 128), 256, 0, stream>>>(
            h, wqkv_h, wqkv_l, biasqkv, nullptr, big, QKVLD, DM, DM);

        qk_sample_kernel<<<(BATCH * NH * SEQ) / 4, 256, 0, stream>>>(
            big, idx_sample + li * SEQ * NSAMP, Mbuf);
        topk_part<<<dim3(BATCH * NH, 8), 256, 0, stream>>>(Mbuf, cand);
        topk_merge<<<BATCH * NH, 256, 0, stream>>>(cand, idx_top);
        hipMemsetAsync(vmean, 0, BATCH * NH * HD * sizeof(float), stream);
        vmean_kernel<<<dim3(BATCH * NH, 8), 256, 0, stream>>>(big, vmean);
        fillctx_kernel<<<(TOK * DM) / 256, 256, 0, stream>>>(vmean, tmp);
        spattn_flash<<<dim3(BATCH * NH, 4), 256, 0, stream>>>(big, idx_top, opart, mspart);
        spattn_combine<<<BATCH * NH, 256, 0, stream>>>(opart, mspart, idx_top, tmp);

        gemm_split<false, true><<<dim3(DM / 128, TOK / 128), 256, 0, stream>>>(
            tmp, wo_h, wo_l, bo_i, h, h, DM, DM, DM);
        ln_kernel<<<TOK, 256, 0, stream>>>(h, g1_i, be1_i, h);

        gemm_split<true, false><<<dim3(DFF / 128, TOK / 128), 256, 0, stream>>>(
            h, w1_h, w1_l, b1_i, nullptr, big, DFF, DM, DM);
        gemm_split<false, true><<<dim3(DM / 128, TOK / 128), 256, 0, stream>>>(
            big, w2_h, w2_l, b2_i, h, tmp, DM, DFF, DFF);
        ln_kernel<<<TOK, 256, 0, stream>>>(tmp, g2_i, be2_i, h);
    }

    ln_kernel<<<TOK, 256, 0, stream>>>(h, g_enc, b_enc, tmp);
    head_kernel<<<BATCH, 256, 0, stream>>>(tmp, W_pre, b_pre, W_fc, b_fc, out);
}